// Round 1
// baseline (776.725 us; speedup 1.0000x reference)
//
#include <hip/hip_runtime.h>
#include <stdint.h>

// Problem: B=2, S=2048, D=2048, H=16, HD=128, M = B*S = 4096
#define BB  2
#define SS  2048
#define DD  2048
#define HH  16
#define HDD 128
#define MM  (BB * SS)

typedef __attribute__((ext_vector_type(8))) short  short8;
typedef __attribute__((ext_vector_type(4))) float  f32x4;
typedef unsigned int   u32;
typedef unsigned short u16;
typedef __attribute__((ext_vector_type(4))) u16 u16x4;

static __device__ __forceinline__ u16 f2bf(float f) {
  u32 u = __builtin_bit_cast(u32, f);
  u32 r = u + 0x7fffu + ((u >> 16) & 1u);
  return (u16)(r >> 16);
}
static __device__ __forceinline__ float bf2f(u16 h) {
  u32 u = ((u32)h) << 16;
  return __builtin_bit_cast(float, u);
}

// ---------------- fp32 -> bf16 conversion (vectorized) ----------------
__global__ void cvt_kernel(const float* __restrict__ src, u16* __restrict__ dst, int n4) {
  int i = blockIdx.x * blockDim.x + threadIdx.x;
  if (i >= n4) return;
  f32x4 v = *(const f32x4*)(src + (size_t)i * 4);
  u16x4 o;
#pragma unroll
  for (int j = 0; j < 4; ++j) o[j] = f2bf(v[j]);
  *(u16x4*)(dst + (size_t)i * 4) = o;
}

// ---------------- RoPE (in-place on bf16 [B*S, H, HD] tensor) ----------------
__global__ void rope_kernel(u16* __restrict__ T, const float* __restrict__ fc,
                            const float* __restrict__ fs) {
  int i = blockIdx.x * blockDim.x + threadIdx.x;
  const int total = MM * HH * (HDD / 2);
  if (i >= total) return;
  int pi   = i & 63;        // pair index within head
  int rest = i >> 6;        // (b*S + s)*H + h
  int s_   = (rest >> 4) & (SS - 1);
  size_t off = (size_t)rest * HDD + (size_t)pi * 2;
  u32 v = *(u32*)(T + off);
  float re = bf2f((u16)(v & 0xffffu));
  float im = bf2f((u16)(v >> 16));
  float c  = fc[s_ * 64 + pi];
  float sn = fs[s_ * 64 + pi];
  float ore = re * c - im * sn;
  float oim = re * sn + im * c;
  u32 o = (u32)f2bf(ore) | ((u32)f2bf(oim) << 16);
  *(u32*)(T + off) = o;
}

// ---------------- GEMM: C[M,N] = A[M,K] * B[N,K]^T (bf16 in, bf16/fp32 out) ----------------
// 128x128 tile, BK=32, 4 waves (2x2, each 64x64 = 4x4 fragments of 16x16x32 MFMA)
template <typename OutT>
__global__ __launch_bounds__(256) void gemm_bt(const u16* __restrict__ A,
                                               const u16* __restrict__ Bw,
                                               OutT* __restrict__ C,
                                               int M, int N, int K) {
  __shared__ __align__(16) u16 Al[128 * 32];
  __shared__ __align__(16) u16 Bl[128 * 32];
  const int tid  = threadIdx.x;
  const int wave = tid >> 6, lane = tid & 63;
  const int m0 = blockIdx.y * 128, n0 = blockIdx.x * 128;
  const int wr = (wave >> 1) * 64, wc = (wave & 1) * 64;
  const int lrow = lane & 15, lk = (lane >> 4) * 8;

  f32x4 acc[4][4] = {};

  for (int k0 = 0; k0 < K; k0 += 32) {
    __syncthreads();
#pragma unroll
    for (int i = 0; i < 2; ++i) {
      int idx = tid + i * 256;                 // 512 16B chunks per tile
      int row = idx >> 2, kc = (idx & 3) * 8;
      const u16* ga = A  + (size_t)(m0 + row) * K + k0 + kc;
      const u16* gb = Bw + (size_t)(n0 + row) * K + k0 + kc;
      __builtin_amdgcn_global_load_lds((const __attribute__((address_space(1))) u32*)ga,
                                       (__attribute__((address_space(3))) u32*)(Al + idx * 8),
                                       16, 0, 0);
      __builtin_amdgcn_global_load_lds((const __attribute__((address_space(1))) u32*)gb,
                                       (__attribute__((address_space(3))) u32*)(Bl + idx * 8),
                                       16, 0, 0);
    }
    __syncthreads();

    short8 af[4], bfr[4];
#pragma unroll
    for (int t = 0; t < 4; ++t) {
      af[t]  = *(const short8*)(Al + (wr + t * 16 + lrow) * 32 + lk);
      bfr[t] = *(const short8*)(Bl + (wc + t * 16 + lrow) * 32 + lk);
    }
#pragma unroll
    for (int mt = 0; mt < 4; ++mt)
#pragma unroll
      for (int nt = 0; nt < 4; ++nt)
        acc[mt][nt] = __builtin_amdgcn_mfma_f32_16x16x32_bf16(af[mt], bfr[nt], acc[mt][nt], 0, 0, 0);
  }

  const int dr = (lane >> 4) * 4;
#pragma unroll
  for (int mt = 0; mt < 4; ++mt)
#pragma unroll
    for (int nt = 0; nt < 4; ++nt)
#pragma unroll
      for (int i = 0; i < 4; ++i) {
        size_t r = (size_t)(m0 + wr + mt * 16 + dr + i);
        size_t c = (size_t)(n0 + wc + nt * 16 + lrow);
        float v = acc[mt][nt][i];
        if constexpr (sizeof(OutT) == 2) C[r * N + c] = f2bf(v);
        else                             C[r * N + c] = v;
      }
}

// ---------------- Flash attention (causal), bf16 QKV in [B*S, H, HD] layout ----------------
// Block: 4 waves, 64 Q-rows (16/wave). KV tiles of 32 keys staged in LDS.
__global__ __launch_bounds__(256) void attn_kernel(const u16* __restrict__ Q,
                                                   const u16* __restrict__ K,
                                                   const u16* __restrict__ V,
                                                   u16* __restrict__ O) {
  __shared__ __align__(16) u16 Kl[32 * 128];     // [key][d]
  __shared__ __align__(16) u16 Vt[128 * 32];     // [d][key]
  __shared__ __align__(16) u16 Pl[4][16 * 32];   // per-wave P tile

  const int tid = threadIdx.x, wave = tid >> 6, lane = tid & 63;
  const int q0 = blockIdx.x * 64;
  const int b = blockIdx.y >> 4, h = blockIdx.y & 15;
  const size_t base = ((size_t)b * SS) * DD + (size_t)h * HDD;
  const int lrow = lane & 15, lk = (lane >> 4) * 8, dr = (lane >> 4) * 4;
  const int qw = q0 + wave * 16;

  // Q fragments for this wave's 16 rows (A-operand, k = d-dim)
  short8 qf[4];
#pragma unroll
  for (int kc = 0; kc < 4; ++kc)
    qf[kc] = *(const short8*)(Q + base + (size_t)(qw + lrow) * DD + kc * 32 + lk);

  f32x4 oacc[8] = {};
  float m_i[4], l_i[4];
#pragma unroll
  for (int i = 0; i < 4; ++i) { m_i[i] = -1e30f; l_i[i] = 0.f; }

  const int ktiles = blockIdx.x * 2 + 2;   // keys 0 .. q0+63
  for (int t = 0; t < ktiles; ++t) {
    const int k0 = t * 32;
    __syncthreads();
    // stage K tile linearly via global_load_lds
#pragma unroll
    for (int i = 0; i < 2; ++i) {
      int idx = tid + i * 256;                 // 512 chunks
      int key = idx >> 4, dc = (idx & 15) * 8;
      const u16* gk = K + base + (size_t)(k0 + key) * DD + dc;
      __builtin_amdgcn_global_load_lds((const __attribute__((address_space(1))) u32*)gk,
                                       (__attribute__((address_space(3))) u32*)(Kl + idx * 8),
                                       16, 0, 0);
    }
    // stage V tile transposed (reg path)
#pragma unroll
    for (int i = 0; i < 2; ++i) {
      int idx = tid + i * 256;
      int key = idx >> 4, dc = (idx & 15) * 8;
      short8 v = *(const short8*)(V + base + (size_t)(k0 + key) * DD + dc);
#pragma unroll
      for (int j = 0; j < 8; ++j) Vt[(dc + j) * 32 + key] = (u16)v[j];
    }
    __syncthreads();

    // scores: S[16 q][32 k] = Q * K^T
    f32x4 sacc[2] = {};
#pragma unroll
    for (int nt = 0; nt < 2; ++nt)
#pragma unroll
      for (int kc = 0; kc < 4; ++kc) {
        short8 kf = *(const short8*)(Kl + (nt * 16 + lrow) * 128 + kc * 32 + lk);
        sacc[nt] = __builtin_amdgcn_mfma_f32_16x16x32_bf16(qf[kc], kf, sacc[nt], 0, 0, 0);
      }

    const float scale = 0.08838834764831845f;  // 1/sqrt(128)
    float p[2][4], rmax[4], rsum[4];
#pragma unroll
    for (int i = 0; i < 4; ++i) {
#pragma unroll
      for (int nt = 0; nt < 2; ++nt) {
        float s = sacc[nt][i] * scale;
        int col = k0 + nt * 16 + lrow;
        int row = qw + dr + i;
        if (col > row) s = -1e30f;             // causal mask
        p[nt][i] = s;
      }
      rmax[i] = fmaxf(p[0][i], p[1][i]);
    }
#pragma unroll
    for (int d = 8; d >= 1; d >>= 1)
#pragma unroll
      for (int i = 0; i < 4; ++i)
        rmax[i] = fmaxf(rmax[i], __shfl_xor(rmax[i], d, 64));

#pragma unroll
    for (int i = 0; i < 4; ++i) {
      float mn  = fmaxf(m_i[i], rmax[i]);
      float esc = __expf(m_i[i] - mn);
      m_i[i] = mn;
      float s0 = __expf(p[0][i] - mn);
      float s1 = __expf(p[1][i] - mn);
      p[0][i] = s0; p[1][i] = s1;
      rsum[i] = s0 + s1;
      l_i[i] *= esc;
#pragma unroll
      for (int nt2 = 0; nt2 < 8; ++nt2) oacc[nt2][i] *= esc;
    }
#pragma unroll
    for (int d = 8; d >= 1; d >>= 1)
#pragma unroll
      for (int i = 0; i < 4; ++i)
        rsum[i] += __shfl_xor(rsum[i], d, 64);
#pragma unroll
    for (int i = 0; i < 4; ++i) l_i[i] += rsum[i];

    // P -> LDS (D-layout) then read back in A-layout
    u16* pw = &Pl[wave][0];
#pragma unroll
    for (int nt = 0; nt < 2; ++nt)
#pragma unroll
      for (int i = 0; i < 4; ++i)
        pw[(dr + i) * 32 + nt * 16 + lrow] = f2bf(p[nt][i]);
    asm volatile("s_waitcnt lgkmcnt(0)" ::: "memory");
    __builtin_amdgcn_sched_barrier(0);
    short8 pf = *(const short8*)(pw + lrow * 32 + lk);

    // O += P * V
#pragma unroll
    for (int nt2 = 0; nt2 < 8; ++nt2) {
      short8 vf = *(const short8*)(Vt + (nt2 * 16 + lrow) * 32 + lk);
      oacc[nt2] = __builtin_amdgcn_mfma_f32_16x16x32_bf16(pf, vf, oacc[nt2], 0, 0, 0);
    }
  }

  // epilogue: O /= l, write bf16
#pragma unroll
  for (int nt2 = 0; nt2 < 8; ++nt2)
#pragma unroll
    for (int i = 0; i < 4; ++i) {
      float o = oacc[nt2][i] / l_i[i];
      size_t row = (size_t)(qw + dr + i);
      O[base + row * DD + nt2 * 16 + lrow] = f2bf(o);
    }
}

// ---------------- launcher ----------------
extern "C" void kernel_launch(void* const* d_in, const int* in_sizes, int n_in,
                              void* d_out, int out_size, void* d_ws, size_t ws_size,
                              hipStream_t stream) {
  (void)in_sizes; (void)n_in; (void)out_size; (void)ws_size;
  const float* x  = (const float*)d_in[0];
  const float* wq = (const float*)d_in[1];
  const float* wk = (const float*)d_in[2];
  const float* wv = (const float*)d_in[3];
  const float* wo = (const float*)d_in[4];
  const float* fc = (const float*)d_in[5];
  const float* fs = (const float*)d_in[6];
  float* out = (float*)d_out;

  const size_t BUF = 16777216;  // M*D * 2 bytes = D*D * 2 bytes
  char* ws = (char*)d_ws;
  u16* xb  = (u16*)(ws + 0 * BUF);   // also reused as O (attention output)
  u16* wqb = (u16*)(ws + 1 * BUF);   // also reused as V (post-projection)
  u16* wkb = (u16*)(ws + 2 * BUF);
  u16* wvb = (u16*)(ws + 3 * BUF);
  u16* wob = (u16*)(ws + 4 * BUF);
  u16* Qb  = (u16*)(ws + 5 * BUF);
  u16* Kb  = (u16*)(ws + 6 * BUF);
  u16* Vb  = wqb;
  u16* Ob  = xb;

  const int nxd4 = (MM * DD) / 4;    // 2097152
  const int nwd4 = (DD * DD) / 4;    // 1048576
  cvt_kernel<<<(nxd4 + 255) / 256, 256, 0, stream>>>(x,  xb,  nxd4);
  cvt_kernel<<<(nwd4 + 255) / 256, 256, 0, stream>>>(wq, wqb, nwd4);
  cvt_kernel<<<(nwd4 + 255) / 256, 256, 0, stream>>>(wk, wkb, nwd4);
  cvt_kernel<<<(nwd4 + 255) / 256, 256, 0, stream>>>(wv, wvb, nwd4);
  cvt_kernel<<<(nwd4 + 255) / 256, 256, 0, stream>>>(wo, wob, nwd4);

  dim3 gg(DD / 128, MM / 128);       // (16, 32)
  gemm_bt<u16><<<gg, 256, 0, stream>>>(xb, wqb, Qb, MM, DD, DD);
  gemm_bt<u16><<<gg, 256, 0, stream>>>(xb, wkb, Kb, MM, DD, DD);
  gemm_bt<u16><<<gg, 256, 0, stream>>>(xb, wvb, Vb, MM, DD, DD);

  const int npair = MM * HH * (HDD / 2);  // 4194304
  rope_kernel<<<(npair + 255) / 256, 256, 0, stream>>>(Qb, fc, fs);
  rope_kernel<<<(npair + 255) / 256, 256, 0, stream>>>(Kb, fc, fs);

  attn_kernel<<<dim3(SS / 64, BB * HH), 256, 0, stream>>>(Qb, Kb, Vb, Ob);

  gemm_bt<float><<<gg, 256, 0, stream>>>(Ob, wob, out, MM, DD, DD);
}

// Round 2
// 367.630 us; speedup vs baseline: 2.1128x; 2.1128x over previous
//
#include <hip/hip_runtime.h>
#include <stdint.h>

// Problem: B=2, S=2048, D=2048, H=16, HD=128, M = B*S = 4096
#define BB  2
#define SS  2048
#define DD  2048
#define HH  16
#define HDD 128
#define MM  (BB * SS)

typedef __attribute__((ext_vector_type(8))) short  short8;
typedef __attribute__((ext_vector_type(4))) float  f32x4;
typedef unsigned int   u32;
typedef unsigned short u16;
typedef __attribute__((ext_vector_type(4))) u16 u16x4;

static __device__ __forceinline__ u16 f2bf(float f) {
  u32 u = __builtin_bit_cast(u32, f);
  u32 r = u + 0x7fffu + ((u >> 16) & 1u);
  return (u16)(r >> 16);
}
static __device__ __forceinline__ float bf2f(u16 h) {
  u32 u = ((u32)h) << 16;
  return __builtin_bit_cast(float, u);
}

// ---------------- fp32 -> bf16 conversion (vectorized) ----------------
__global__ void cvt_kernel(const float* __restrict__ src, u16* __restrict__ dst, int n4) {
  int i = blockIdx.x * blockDim.x + threadIdx.x;
  if (i >= n4) return;
  f32x4 v = *(const f32x4*)(src + (size_t)i * 4);
  u16x4 o;
#pragma unroll
  for (int j = 0; j < 4; ++j) o[j] = f2bf(v[j]);
  *(u16x4*)(dst + (size_t)i * 4) = o;
}

// ---------------- RoPE (in-place on bf16 [B*S, H, HD] tensor) ----------------
__global__ void rope_kernel(u16* __restrict__ T, const float* __restrict__ fc,
                            const float* __restrict__ fs) {
  int i = blockIdx.x * blockDim.x + threadIdx.x;
  const int total = MM * HH * (HDD / 2);
  if (i >= total) return;
  int pi   = i & 63;        // pair index within head
  int rest = i >> 6;        // (b*S + s)*H + h
  int s_   = (rest >> 4) & (SS - 1);
  size_t off = (size_t)rest * HDD + (size_t)pi * 2;
  u32 v = *(u32*)(T + off);
  float re = bf2f((u16)(v & 0xffffu));
  float im = bf2f((u16)(v >> 16));
  float c  = fc[s_ * 64 + pi];
  float sn = fs[s_ * 64 + pi];
  float ore = re * c - im * sn;
  float oim = re * sn + im * c;
  u32 o = (u32)f2bf(ore) | ((u32)f2bf(oim) << 16);
  *(u32*)(T + off) = o;
}

// ---------------- GEMM: C[M,N] = A[M,K] * B[N,K]^T ----------------
// MODE 0: bf16 out (row-major [M,N])
// MODE 1: f32 out  (row-major [M,N])
// MODE 2: bf16 out transposed per batch: Vt[b*2048 + n][s], s = m % 2048
template <int MODE, typename OutT>
__global__ __launch_bounds__(256) void gemm_bt(const u16* __restrict__ A,
                                               const u16* __restrict__ Bw,
                                               OutT* __restrict__ C,
                                               int M, int N, int K) {
  __shared__ __align__(16) u16 Al[128 * 32];
  __shared__ __align__(16) u16 Bl[128 * 32];
  const int tid  = threadIdx.x;
  const int wave = tid >> 6, lane = tid & 63;
  const int m0 = blockIdx.y * 128, n0 = blockIdx.x * 128;
  const int wr = (wave >> 1) * 64, wc = (wave & 1) * 64;
  const int lrow = lane & 15, lk = (lane >> 4) * 8;

  f32x4 acc[4][4] = {};

  for (int k0 = 0; k0 < K; k0 += 32) {
    __syncthreads();
#pragma unroll
    for (int i = 0; i < 2; ++i) {
      int idx = tid + i * 256;                 // 512 16B chunks per tile
      int row = idx >> 2, kc = (idx & 3) * 8;
      const u16* ga = A  + (size_t)(m0 + row) * K + k0 + kc;
      const u16* gb = Bw + (size_t)(n0 + row) * K + k0 + kc;
      __builtin_amdgcn_global_load_lds((const __attribute__((address_space(1))) u32*)ga,
                                       (__attribute__((address_space(3))) u32*)(Al + idx * 8),
                                       16, 0, 0);
      __builtin_amdgcn_global_load_lds((const __attribute__((address_space(1))) u32*)gb,
                                       (__attribute__((address_space(3))) u32*)(Bl + idx * 8),
                                       16, 0, 0);
    }
    __syncthreads();

    short8 af[4], bfr[4];
#pragma unroll
    for (int t = 0; t < 4; ++t) {
      af[t]  = *(const short8*)(Al + (wr + t * 16 + lrow) * 32 + lk);
      bfr[t] = *(const short8*)(Bl + (wc + t * 16 + lrow) * 32 + lk);
    }
#pragma unroll
    for (int mt = 0; mt < 4; ++mt)
#pragma unroll
      for (int nt = 0; nt < 4; ++nt)
        acc[mt][nt] = __builtin_amdgcn_mfma_f32_16x16x32_bf16(af[mt], bfr[nt], acc[mt][nt], 0, 0, 0);
  }

  const int dr = (lane >> 4) * 4;
#pragma unroll
  for (int mt = 0; mt < 4; ++mt)
#pragma unroll
    for (int nt = 0; nt < 4; ++nt) {
      if constexpr (MODE == 2) {
        // transposed store: 4 consecutive rows (tokens) -> 4 consecutive s at one Vt row
        int rr = m0 + wr + mt * 16 + dr;           // token index, multiple of 4
        int cc = n0 + wc + nt * 16 + lrow;         // h*128+d
        int b  = rr >> 11, s0 = rr & 2047;
        size_t vrow = (size_t)b * 2048 + cc;
        u16x4 pk;
#pragma unroll
        for (int i = 0; i < 4; ++i) pk[i] = f2bf(acc[mt][nt][i]);
        *(u16x4*)((u16*)C + vrow * 2048 + s0) = pk;
      } else {
#pragma unroll
        for (int i = 0; i < 4; ++i) {
          size_t r = (size_t)(m0 + wr + mt * 16 + dr + i);
          size_t c = (size_t)(n0 + wc + nt * 16 + lrow);
          float v = acc[mt][nt][i];
          if constexpr (MODE == 0) ((u16*)C)[r * N + c]  = f2bf(v);
          else                     ((float*)C)[r * N + c] = v;
        }
      }
    }
}

// ---------------- Flash attention (causal) ----------------
// Q,K: bf16 [B*S, H*HD] (token-major). Vt: bf16 [(b*H+h)*HD + d][s].
// Block: 4 waves, 64 Q-rows (16/wave). KV tiles of 64 keys, XOR-swizzled LDS.
// Grid x pairs Q-tiles (x, 31-x) for causal load balance: 33 KV tiles/block.
__global__ __launch_bounds__(256) void attn_kernel(const u16* __restrict__ Q,
                                                   const u16* __restrict__ K,
                                                   const u16* __restrict__ Vt,
                                                   u16* __restrict__ O) {
  __shared__ __align__(16) u16 Kl[64 * 128];     // [key][d], swizzled
  __shared__ __align__(16) u16 Vl[128 * 64];     // [d][key], swizzled
  __shared__ __align__(16) u16 Pl[4][16 * 64];   // per-wave P tile, swizzled

  const int tid = threadIdx.x, wave = tid >> 6, lane = tid & 63;
  const int x = blockIdx.x;
  const int bh = blockIdx.y, b = bh >> 4, h = bh & 15;
  const size_t base    = ((size_t)b * SS) * DD + (size_t)h * HDD;
  const size_t vt_base = (size_t)bh * HDD * SS;
  const int lrow = lane & 15, khalf = lane >> 4;
  const int lk = khalf * 8, dr = khalf * 4;
  const int swz = (lrow & 7) << 4;               // byte-domain read swizzle
  u16* pw = &Pl[wave][0];

  for (int qsel = 0; qsel < 2; ++qsel) {
    const int qt = qsel ? (31 - x) : x;
    const int qw = qt * 64 + wave * 16;

    short8 qf[4];
#pragma unroll
    for (int kc = 0; kc < 4; ++kc)
      qf[kc] = *(const short8*)(Q + base + (size_t)(qw + lrow) * DD + kc * 32 + lk);

    f32x4 oacc[8] = {};
    float m_i[4], l_i[4];
#pragma unroll
    for (int i = 0; i < 4; ++i) { m_i[i] = -1e30f; l_i[i] = 0.f; }

    const int ntiles = qt + 1;
    for (int kt = 0; kt < ntiles; ++kt) {
      const int k0 = kt * 64;
      __syncthreads();
      // stage K (64x128) and Vt (128x64), pre-swizzled global source
#pragma unroll
      for (int i = 0; i < 4; ++i) {
        int idx = tid + i * 256;
        int kr = idx >> 4, c = idx & 15;
        const u16* gk = K + base + (size_t)(k0 + kr) * DD + ((c ^ (kr & 7)) * 8);
        __builtin_amdgcn_global_load_lds((const __attribute__((address_space(1))) u32*)gk,
                                         (__attribute__((address_space(3))) u32*)(Kl + idx * 8),
                                         16, 0, 0);
        int dv = idx >> 3, c2 = idx & 7;
        const u16* gv = Vt + vt_base + (size_t)dv * SS + k0 + ((c2 ^ (dv & 7)) * 8);
        __builtin_amdgcn_global_load_lds((const __attribute__((address_space(1))) u32*)gv,
                                         (__attribute__((address_space(3))) u32*)(Vl + idx * 8),
                                         16, 0, 0);
      }
      __syncthreads();

      // QK^T: S[16q][64k]
      f32x4 sacc[4] = {};
      __builtin_amdgcn_s_setprio(1);
#pragma unroll
      for (int nt = 0; nt < 4; ++nt)
#pragma unroll
        for (int kc = 0; kc < 4; ++kc) {
          int byteoff = ((nt * 16 + lrow) * 256 + kc * 64 + khalf * 16) ^ swz;
          short8 kf = *(const short8*)(Kl + (byteoff >> 1));
          sacc[nt] = __builtin_amdgcn_mfma_f32_16x16x32_bf16(qf[kc], kf, sacc[nt], 0, 0, 0);
        }
      __builtin_amdgcn_s_setprio(0);

      const float scale = 0.08838834764831845f;  // 1/sqrt(128)
      float p[4][4], rmax[4], rsum[4];
      const bool diag = (kt == qt);
#pragma unroll
      for (int i = 0; i < 4; ++i) {
#pragma unroll
        for (int nt = 0; nt < 4; ++nt) {
          float s = sacc[nt][i] * scale;
          if (diag && (k0 + nt * 16 + lrow > qw + dr + i)) s = -1e30f;
          p[nt][i] = s;
        }
        rmax[i] = fmaxf(fmaxf(p[0][i], p[1][i]), fmaxf(p[2][i], p[3][i]));
      }
#pragma unroll
      for (int d = 8; d >= 1; d >>= 1)
#pragma unroll
        for (int i = 0; i < 4; ++i)
          rmax[i] = fmaxf(rmax[i], __shfl_xor(rmax[i], d, 64));

#pragma unroll
      for (int i = 0; i < 4; ++i) {
        float mn  = fmaxf(m_i[i], rmax[i]);
        float esc = __expf(m_i[i] - mn);
        m_i[i] = mn;
        float sum = 0.f;
#pragma unroll
        for (int nt = 0; nt < 4; ++nt) {
          p[nt][i] = __expf(p[nt][i] - mn);
          sum += p[nt][i];
        }
        rsum[i] = sum;
        l_i[i] *= esc;
#pragma unroll
        for (int nt2 = 0; nt2 < 8; ++nt2) oacc[nt2][i] *= esc;
      }
#pragma unroll
      for (int d = 8; d >= 1; d >>= 1)
#pragma unroll
        for (int i = 0; i < 4; ++i)
          rsum[i] += __shfl_xor(rsum[i], d, 64);
#pragma unroll
      for (int i = 0; i < 4; ++i) l_i[i] += rsum[i];

      // P -> LDS (swizzled), read back in A-fragment layout
#pragma unroll
      for (int nt = 0; nt < 4; ++nt)
#pragma unroll
        for (int i = 0; i < 4; ++i) {
          int prow = dr + i;
          int pcol = (nt * 16 + lrow) ^ ((prow & 7) << 3);
          pw[prow * 64 + pcol] = f2bf(p[nt][i]);
        }
      asm volatile("s_waitcnt lgkmcnt(0)" ::: "memory");
      __builtin_amdgcn_sched_barrier(0);
      short8 pf[2];
#pragma unroll
      for (int ks = 0; ks < 2; ++ks) {
        int pcol0 = (ks * 32 + lk) ^ ((lrow & 7) << 3);
        pf[ks] = *(const short8*)(pw + lrow * 64 + pcol0);
      }

      // O += P * V
      __builtin_amdgcn_s_setprio(1);
#pragma unroll
      for (int nt2 = 0; nt2 < 8; ++nt2)
#pragma unroll
        for (int ks = 0; ks < 2; ++ks) {
          int byteoff = ((nt2 * 16 + lrow) * 128 + ks * 64 + khalf * 16) ^ swz;
          short8 vf = *(const short8*)(Vl + (byteoff >> 1));
          oacc[nt2] = __builtin_amdgcn_mfma_f32_16x16x32_bf16(pf[ks], vf, oacc[nt2], 0, 0, 0);
        }
      __builtin_amdgcn_s_setprio(0);
    }

    // epilogue: O /= l, write bf16
#pragma unroll
    for (int nt2 = 0; nt2 < 8; ++nt2)
#pragma unroll
      for (int i = 0; i < 4; ++i) {
        float o = oacc[nt2][i] / l_i[i];
        size_t row = (size_t)(qw + dr + i);
        O[base + row * DD + nt2 * 16 + lrow] = f2bf(o);
      }
  }
}

// ---------------- launcher ----------------
extern "C" void kernel_launch(void* const* d_in, const int* in_sizes, int n_in,
                              void* d_out, int out_size, void* d_ws, size_t ws_size,
                              hipStream_t stream) {
  (void)in_sizes; (void)n_in; (void)out_size; (void)ws_size;
  const float* x  = (const float*)d_in[0];
  const float* wq = (const float*)d_in[1];
  const float* wk = (const float*)d_in[2];
  const float* wv = (const float*)d_in[3];
  const float* wo = (const float*)d_in[4];
  const float* fc = (const float*)d_in[5];
  const float* fs = (const float*)d_in[6];
  float* out = (float*)d_out;

  const size_t BUF = 16777216;  // M*D * 2 bytes = D*D * 2 bytes
  char* ws = (char*)d_ws;
  u16* xb  = (u16*)(ws + 0 * BUF);   // also reused as O (attention output)
  u16* wqb = (u16*)(ws + 1 * BUF);   // also reused as Vt (post-projection, transposed)
  u16* wkb = (u16*)(ws + 2 * BUF);
  u16* wvb = (u16*)(ws + 3 * BUF);
  u16* wob = (u16*)(ws + 4 * BUF);
  u16* Qb  = (u16*)(ws + 5 * BUF);
  u16* Kb  = (u16*)(ws + 6 * BUF);
  u16* Vtb = wqb;
  u16* Ob  = xb;

  const int nxd4 = (MM * DD) / 4;    // 2097152
  const int nwd4 = (DD * DD) / 4;    // 1048576
  cvt_kernel<<<(nxd4 + 255) / 256, 256, 0, stream>>>(x,  xb,  nxd4);
  cvt_kernel<<<(nwd4 + 255) / 256, 256, 0, stream>>>(wq, wqb, nwd4);
  cvt_kernel<<<(nwd4 + 255) / 256, 256, 0, stream>>>(wk, wkb, nwd4);
  cvt_kernel<<<(nwd4 + 255) / 256, 256, 0, stream>>>(wv, wvb, nwd4);
  cvt_kernel<<<(nwd4 + 255) / 256, 256, 0, stream>>>(wo, wob, nwd4);

  dim3 gg(DD / 128, MM / 128);       // (16, 32)
  gemm_bt<0, u16><<<gg, 256, 0, stream>>>(xb, wqb, Qb, MM, DD, DD);
  gemm_bt<0, u16><<<gg, 256, 0, stream>>>(xb, wkb, Kb, MM, DD, DD);
  gemm_bt<2, u16><<<gg, 256, 0, stream>>>(xb, wvb, Vtb, MM, DD, DD);

  const int npair = MM * HH * (HDD / 2);  // 4194304
  rope_kernel<<<(npair + 255) / 256, 256, 0, stream>>>(Qb, fc, fs);
  rope_kernel<<<(npair + 255) / 256, 256, 0, stream>>>(Kb, fc, fs);

  attn_kernel<<<dim3(16, BB * HH), 256, 0, stream>>>(Qb, Kb, Vtb, Ob);

  gemm_bt<1, float><<<gg, 256, 0, stream>>>(Ob, wob, out, MM, DD, DD);
}

// Round 3
// 340.982 us; speedup vs baseline: 2.2779x; 1.0781x over previous
//
#include <hip/hip_runtime.h>
#include <stdint.h>

// Problem: B=2, S=2048, D=2048, H=16, HD=128, M = B*S = 4096
#define BB  2
#define SS  2048
#define DD  2048
#define HH  16
#define HDD 128
#define MM  (BB * SS)

typedef __attribute__((ext_vector_type(8))) short  short8;
typedef __attribute__((ext_vector_type(4))) float  f32x4;
typedef unsigned int   u32;
typedef unsigned short u16;
typedef __attribute__((ext_vector_type(4))) u16 u16x4;

static __device__ __forceinline__ u16 f2bf(float f) {
  u32 u = __builtin_bit_cast(u32, f);
  u32 r = u + 0x7fffu + ((u >> 16) & 1u);
  return (u16)(r >> 16);
}

// ---------------- fused fp32 -> bf16 conversion for all 5 tensors ----------------
__global__ void cvt_all(const float* __restrict__ x,  const float* __restrict__ wq,
                        const float* __restrict__ wk, const float* __restrict__ wv,
                        const float* __restrict__ wo,
                        u16* __restrict__ xb,  u16* __restrict__ wqb,
                        u16* __restrict__ wkb, u16* __restrict__ wvb,
                        u16* __restrict__ wob) {
  const int NX = (MM * DD) / 4;        // 2097152 chunks for x
  const int NW = (DD * DD) / 4;        // 1048576 chunks per weight
  int i = blockIdx.x * blockDim.x + threadIdx.x;
  const float* s; u16* d; int off;
  if (i < NX) { s = x; d = xb; off = i; }
  else {
    int j = i - NX; int w = j >> 20; off = j & (NW - 1);
    s = (w == 0) ? wq : (w == 1) ? wk : (w == 2) ? wv : wo;
    d = (w == 0) ? wqb : (w == 1) ? wkb : (w == 2) ? wvb : wob;
  }
  f32x4 v = *(const f32x4*)(s + (size_t)off * 4);
  u16x4 o;
#pragma unroll
  for (int j = 0; j < 4; ++j) o[j] = f2bf(v[j]);
  *(u16x4*)(d + (size_t)off * 4) = o;
}

// ---------------- GEMM: C[M,N] = A[M,K] * B[N,K]^T ----------------
// MODE 0: bf16 out (row-major [M,N])
// MODE 1: f32 out  (row-major [M,N])
// MODE 2: bf16 out transposed per batch: Vt[b*2048 + n][s], s = m % 2048
// MODE 3: bf16 out with fused RoPE (for Q/K projections)
template <int MODE, typename OutT>
__global__ __launch_bounds__(256) void gemm_bt(const u16* __restrict__ A,
                                               const u16* __restrict__ Bw,
                                               OutT* __restrict__ C,
                                               int M, int N, int K,
                                               const float* __restrict__ fc,
                                               const float* __restrict__ fs) {
  __shared__ __align__(16) u16 Al[128 * 32];
  __shared__ __align__(16) u16 Bl[128 * 32];
  const int tid  = threadIdx.x;
  const int wave = tid >> 6, lane = tid & 63;
  const int m0 = blockIdx.y * 128, n0 = blockIdx.x * 128;
  const int wr = (wave >> 1) * 64, wc = (wave & 1) * 64;
  const int lrow = lane & 15, lk = (lane >> 4) * 8;

  f32x4 acc[4][4] = {};

  for (int k0 = 0; k0 < K; k0 += 32) {
    __syncthreads();
#pragma unroll
    for (int i = 0; i < 2; ++i) {
      int idx = tid + i * 256;                 // 512 16B chunks per tile
      int row = idx >> 2, kc = (idx & 3) * 8;
      const u16* ga = A  + (size_t)(m0 + row) * K + k0 + kc;
      const u16* gb = Bw + (size_t)(n0 + row) * K + k0 + kc;
      __builtin_amdgcn_global_load_lds((const __attribute__((address_space(1))) u32*)ga,
                                       (__attribute__((address_space(3))) u32*)(Al + idx * 8),
                                       16, 0, 0);
      __builtin_amdgcn_global_load_lds((const __attribute__((address_space(1))) u32*)gb,
                                       (__attribute__((address_space(3))) u32*)(Bl + idx * 8),
                                       16, 0, 0);
    }
    __syncthreads();

    short8 af[4], bfr[4];
#pragma unroll
    for (int t = 0; t < 4; ++t) {
      af[t]  = *(const short8*)(Al + (wr + t * 16 + lrow) * 32 + lk);
      bfr[t] = *(const short8*)(Bl + (wc + t * 16 + lrow) * 32 + lk);
    }
#pragma unroll
    for (int mt = 0; mt < 4; ++mt)
#pragma unroll
      for (int nt = 0; nt < 4; ++nt)
        acc[mt][nt] = __builtin_amdgcn_mfma_f32_16x16x32_bf16(af[mt], bfr[nt], acc[mt][nt], 0, 0, 0);
  }

  const int dr = (lane >> 4) * 4;
#pragma unroll
  for (int mt = 0; mt < 4; ++mt)
#pragma unroll
    for (int nt = 0; nt < 4; ++nt) {
      if constexpr (MODE == 2) {
        // transposed store: 4 consecutive rows (tokens) -> 4 consecutive s at one Vt row
        int rr = m0 + wr + mt * 16 + dr;           // token index, multiple of 4
        int cc = n0 + wc + nt * 16 + lrow;         // h*128+d
        int b  = rr >> 11, s0 = rr & 2047;
        size_t vrow = (size_t)b * 2048 + cc;
        u16x4 pk;
#pragma unroll
        for (int i = 0; i < 4; ++i) pk[i] = f2bf(acc[mt][nt][i]);
        *(u16x4*)((u16*)C + vrow * 2048 + s0) = pk;
      } else if constexpr (MODE == 3) {
        // fused RoPE: pair partner value lives in lane^1 (col parity == lrow bit0)
        int c = n0 + wc + nt * 16 + lrow;
        int dh = c & 127, pi = dh >> 1;
        float sgn = (dh & 1) ? 1.f : -1.f;
#pragma unroll
        for (int i = 0; i < 4; ++i) {
          int r = m0 + wr + mt * 16 + dr + i;
          int s_ = r & (SS - 1);
          float cc_ = fc[s_ * 64 + pi];
          float ss_ = fs[s_ * 64 + pi];
          float v  = acc[mt][nt][i];
          float pv = __shfl_xor(v, 1, 64);
          ((u16*)C)[(size_t)r * N + c] = f2bf(v * cc_ + pv * (sgn * ss_));
        }
      } else {
#pragma unroll
        for (int i = 0; i < 4; ++i) {
          size_t r = (size_t)(m0 + wr + mt * 16 + dr + i);
          size_t cix = (size_t)(n0 + wc + nt * 16 + lrow);
          float v = acc[mt][nt][i];
          if constexpr (MODE == 0) ((u16*)C)[r * N + cix]  = f2bf(v);
          else                     ((float*)C)[r * N + cix] = v;
        }
      }
    }
}

// ---------------- Flash attention (causal), 2-phase pipelined staging ----------------
// Q,K: bf16 [B*S, H*HD] (token-major, roped). Vt: bf16 [(b*H+h)*HD + d][s].
// Block: 4 waves, 64 Q-rows (16/wave). KV tiles of 64 keys, XOR-swizzled, double-buffered.
// Grid x pairs Q-tiles (x, 31-x): 33 KV tiles/block.
__global__ __launch_bounds__(256) void attn_kernel(const u16* __restrict__ Q,
                                                   const u16* __restrict__ K,
                                                   const u16* __restrict__ Vt,
                                                   u16* __restrict__ O) {
  __shared__ __align__(16) u16 Kl[2][64 * 128];   // [buf][key][d], swizzled
  __shared__ __align__(16) u16 Vl[2][128 * 64];   // [buf][d][key], swizzled
  __shared__ __align__(16) u16 Pl[4][16 * 64];    // per-wave P tile, swizzled

  const int tid = threadIdx.x, wave = tid >> 6, lane = tid & 63;
  const int x = blockIdx.x;
  const int bh = blockIdx.y, b = bh >> 4, h = bh & 15;
  const size_t base    = ((size_t)b * SS) * DD + (size_t)h * HDD;
  const size_t vt_base = (size_t)bh * HDD * SS;
  const int lrow = lane & 15, khalf = lane >> 4;
  const int lk = khalf * 8, dr = khalf * 4;
  const int swz = (lrow & 7) << 4;               // byte-domain read swizzle
  u16* pw = &Pl[wave][0];

#define STAGE(KT, BUF)                                                              \
  {                                                                                 \
    int k0s = (KT) * 64;                                                            \
    _Pragma("unroll")                                                               \
    for (int i_ = 0; i_ < 4; ++i_) {                                                \
      int idx = tid + i_ * 256;                                                     \
      int kr = idx >> 4, c_ = idx & 15;                                             \
      const u16* gk = K + base + (size_t)(k0s + kr) * DD + ((c_ ^ (kr & 7)) * 8);   \
      __builtin_amdgcn_global_load_lds((const __attribute__((address_space(1))) u32*)gk, \
                                       (__attribute__((address_space(3))) u32*)(&Kl[BUF][0] + idx * 8), \
                                       16, 0, 0);                                   \
      int dv = idx >> 3, c2 = idx & 7;                                              \
      const u16* gv = Vt + vt_base + (size_t)dv * SS + k0s + ((c2 ^ (dv & 7)) * 8); \
      __builtin_amdgcn_global_load_lds((const __attribute__((address_space(1))) u32*)gv, \
                                       (__attribute__((address_space(3))) u32*)(&Vl[BUF][0] + idx * 8), \
                                       16, 0, 0);                                   \
    }                                                                               \
  }

  for (int qsel = 0; qsel < 2; ++qsel) {
    const int qt = qsel ? (31 - x) : x;
    const int qw = qt * 64 + wave * 16;

    short8 qf[4];
#pragma unroll
    for (int kc = 0; kc < 4; ++kc)
      qf[kc] = *(const short8*)(Q + base + (size_t)(qw + lrow) * DD + kc * 32 + lk);

    f32x4 oacc[8] = {};
    float m_i[4], l_p[4];
#pragma unroll
    for (int i = 0; i < 4; ++i) { m_i[i] = -1e30f; l_p[i] = 0.f; }

    const int ntiles = qt + 1;
    __syncthreads();                    // previous qsel's reads fully done
    STAGE(0, 0);

    for (int kt = 0; kt < ntiles; ++kt) {
      const int cur = kt & 1;
      const int k0 = kt * 64;
      if (kt + 1 < ntiles) {
        STAGE(kt + 1, cur ^ 1);        // issue next tile's loads first
        asm volatile("s_waitcnt vmcnt(8)" ::: "memory");  // current tile done; next in flight
      } else {
        asm volatile("s_waitcnt vmcnt(0)" ::: "memory");
      }
      __syncthreads();                  // staging visible to all waves

      const u16* Kb_ = &Kl[cur][0];
      const u16* Vb_ = &Vl[cur][0];

      // QK^T: S[16q][64k]
      f32x4 sacc[4] = {};
      __builtin_amdgcn_s_setprio(1);
#pragma unroll
      for (int nt = 0; nt < 4; ++nt)
#pragma unroll
        for (int kc = 0; kc < 4; ++kc) {
          int byteoff = ((nt * 16 + lrow) * 256 + kc * 64 + khalf * 16) ^ swz;
          short8 kf = *(const short8*)(Kb_ + (byteoff >> 1));
          sacc[nt] = __builtin_amdgcn_mfma_f32_16x16x32_bf16(qf[kc], kf, sacc[nt], 0, 0, 0);
        }
      __builtin_amdgcn_s_setprio(0);

      const float scale = 0.08838834764831845f;  // 1/sqrt(128)
      float p[4][4], rmax[4];
      const bool diag = (kt == qt);
#pragma unroll
      for (int i = 0; i < 4; ++i) {
#pragma unroll
        for (int nt = 0; nt < 4; ++nt) {
          float s = sacc[nt][i] * scale;
          if (diag && (k0 + nt * 16 + lrow > qw + dr + i)) s = -1e30f;
          p[nt][i] = s;
        }
        rmax[i] = fmaxf(fmaxf(p[0][i], p[1][i]), fmaxf(p[2][i], p[3][i]));
      }
#pragma unroll
      for (int d = 8; d >= 1; d >>= 1)
#pragma unroll
        for (int i = 0; i < 4; ++i)
          rmax[i] = fmaxf(rmax[i], __shfl_xor(rmax[i], d, 64));

      // defer-max (T13): only rescale when the running max grew by > 8
      bool need = false;
#pragma unroll
      for (int i = 0; i < 4; ++i) need |= (rmax[i] > m_i[i] + 8.f);
      if (__any(need)) {
#pragma unroll
        for (int i = 0; i < 4; ++i) {
          float mn  = fmaxf(m_i[i], rmax[i]);
          float esc = __expf(m_i[i] - mn);
          m_i[i] = mn;
          l_p[i] *= esc;
#pragma unroll
          for (int nt2 = 0; nt2 < 8; ++nt2) oacc[nt2][i] *= esc;
        }
      }
#pragma unroll
      for (int i = 0; i < 4; ++i) {
        float sum = 0.f;
#pragma unroll
        for (int nt = 0; nt < 4; ++nt) {
          p[nt][i] = __expf(p[nt][i] - m_i[i]);
          sum += p[nt][i];
        }
        l_p[i] += sum;                 // per-lane partial; reduced once in epilogue
      }

      // P -> LDS (swizzled), read back in A-fragment layout
#pragma unroll
      for (int nt = 0; nt < 4; ++nt)
#pragma unroll
        for (int i = 0; i < 4; ++i) {
          int prow = dr + i;
          int pcol = (nt * 16 + lrow) ^ ((prow & 7) << 3);
          pw[prow * 64 + pcol] = f2bf(p[nt][i]);
        }
      asm volatile("s_waitcnt lgkmcnt(0)" ::: "memory");
      __builtin_amdgcn_sched_barrier(0);
      short8 pf[2];
#pragma unroll
      for (int ks = 0; ks < 2; ++ks) {
        int pcol0 = (ks * 32 + lk) ^ ((lrow & 7) << 3);
        pf[ks] = *(const short8*)(pw + lrow * 64 + pcol0);
      }

      // O += P * V
      __builtin_amdgcn_s_setprio(1);
#pragma unroll
      for (int nt2 = 0; nt2 < 8; ++nt2)
#pragma unroll
        for (int ks = 0; ks < 2; ++ks) {
          int byteoff = ((nt2 * 16 + lrow) * 128 + ks * 64 + khalf * 16) ^ swz;
          short8 vf = *(const short8*)(Vb_ + (byteoff >> 1));
          oacc[nt2] = __builtin_amdgcn_mfma_f32_16x16x32_bf16(pf[ks], vf, oacc[nt2], 0, 0, 0);
        }
      __builtin_amdgcn_s_setprio(0);
      __syncthreads();                  // all reads of buf[cur] done before it is restaged
    }

    // epilogue: reduce l across the 16-lane row group, O /= l, write bf16
#pragma unroll
    for (int d = 8; d >= 1; d >>= 1)
#pragma unroll
      for (int i = 0; i < 4; ++i)
        l_p[i] += __shfl_xor(l_p[i], d, 64);
#pragma unroll
    for (int nt2 = 0; nt2 < 8; ++nt2)
#pragma unroll
      for (int i = 0; i < 4; ++i) {
        float o = oacc[nt2][i] / l_p[i];
        size_t row = (size_t)(qw + dr + i);
        O[base + row * DD + nt2 * 16 + lrow] = f2bf(o);
      }
  }
#undef STAGE
}

// ---------------- launcher ----------------
extern "C" void kernel_launch(void* const* d_in, const int* in_sizes, int n_in,
                              void* d_out, int out_size, void* d_ws, size_t ws_size,
                              hipStream_t stream) {
  (void)in_sizes; (void)n_in; (void)out_size; (void)ws_size;
  const float* x  = (const float*)d_in[0];
  const float* wq = (const float*)d_in[1];
  const float* wk = (const float*)d_in[2];
  const float* wv = (const float*)d_in[3];
  const float* wo = (const float*)d_in[4];
  const float* fc = (const float*)d_in[5];
  const float* fs = (const float*)d_in[6];
  float* out = (float*)d_out;

  const size_t BUF = 16777216;  // M*D * 2 bytes = D*D * 2 bytes
  char* ws = (char*)d_ws;
  u16* xb  = (u16*)(ws + 0 * BUF);   // also reused as O (attention output)
  u16* wqb = (u16*)(ws + 1 * BUF);   // also reused as Vt (post-projection, transposed)
  u16* wkb = (u16*)(ws + 2 * BUF);
  u16* wvb = (u16*)(ws + 3 * BUF);
  u16* wob = (u16*)(ws + 4 * BUF);
  u16* Qb  = (u16*)(ws + 5 * BUF);
  u16* Kb  = (u16*)(ws + 6 * BUF);
  u16* Vtb = wqb;
  u16* Ob  = xb;

  const int ncv = (MM * DD) / 4 + 4 * ((DD * DD) / 4);   // 6291456
  cvt_all<<<ncv / 256, 256, 0, stream>>>(x, wq, wk, wv, wo, xb, wqb, wkb, wvb, wob);

  dim3 gg(DD / 128, MM / 128);       // (16, 32)
  gemm_bt<3, u16><<<gg, 256, 0, stream>>>(xb, wqb, Qb, MM, DD, DD, fc, fs);
  gemm_bt<3, u16><<<gg, 256, 0, stream>>>(xb, wkb, Kb, MM, DD, DD, fc, fs);
  gemm_bt<2, u16><<<gg, 256, 0, stream>>>(xb, wvb, Vtb, MM, DD, DD, fc, fs);

  attn_kernel<<<dim3(16, BB * HH), 256, 0, stream>>>(Qb, Kb, Vtb, Ob);

  gemm_bt<1, float><<<gg, 256, 0, stream>>>(Ob, wob, out, MM, DD, DD, fc, fs);
}

// Round 4
// 334.824 us; speedup vs baseline: 2.3198x; 1.0184x over previous
//
#include <hip/hip_runtime.h>
#include <stdint.h>

// Problem: B=2, S=2048, D=2048, H=16, HD=128, M = B*S = 4096
#define BB  2
#define SS  2048
#define DD  2048
#define HH  16
#define HDD 128
#define MM  (BB * SS)

typedef __attribute__((ext_vector_type(8)))  short short8;
typedef __attribute__((ext_vector_type(4)))  float f32x4;
typedef __attribute__((ext_vector_type(16))) float f32x16;
typedef unsigned int   u32;
typedef unsigned short u16;
typedef __attribute__((ext_vector_type(4))) u16 u16x4;
typedef __attribute__((ext_vector_type(4))) u32 u32x4;

static __device__ __forceinline__ u16 f2bf(float f) {
  u32 u = __builtin_bit_cast(u32, f);
  u32 r = u + 0x7fffu + ((u >> 16) & 1u);
  return (u16)(r >> 16);
}

static __device__ __forceinline__ u32 cvtpk(float a, float b) {
  u32 r;
  asm("v_cvt_pk_bf16_f32 %0, %1, %2" : "=v"(r) : "v"(a), "v"(b));
  return r;
}
static __device__ __forceinline__ void permswap(u32& a, u32& b) {
  asm volatile("v_permlane32_swap_b32 %0, %1" : "+v"(a), "+v"(b));
}

// ---------------- fused fp32 -> bf16 conversion for all 5 tensors ----------------
__global__ void cvt_all(const float* __restrict__ x,  const float* __restrict__ wq,
                        const float* __restrict__ wk, const float* __restrict__ wv,
                        const float* __restrict__ wo,
                        u16* __restrict__ xb,  u16* __restrict__ wqb,
                        u16* __restrict__ wkb, u16* __restrict__ wvb,
                        u16* __restrict__ wob) {
  const int NX = (MM * DD) / 4;        // 2097152 chunks for x
  const int NW = (DD * DD) / 4;        // 1048576 chunks per weight
  int i = blockIdx.x * blockDim.x + threadIdx.x;
  const float* s; u16* d; int off;
  if (i < NX) { s = x; d = xb; off = i; }
  else {
    int j = i - NX; int w = j >> 20; off = j & (NW - 1);
    s = (w == 0) ? wq : (w == 1) ? wk : (w == 2) ? wv : wo;
    d = (w == 0) ? wqb : (w == 1) ? wkb : (w == 2) ? wvb : wob;
  }
  f32x4 v = *(const f32x4*)(s + (size_t)off * 4);
  u16x4 o;
#pragma unroll
  for (int j = 0; j < 4; ++j) o[j] = f2bf(v[j]);
  *(u16x4*)(d + (size_t)off * 4) = o;
}

// ---------------- GEMM: C[M,N] = A[M,K] * B[N,K]^T ----------------
// MODE 0: bf16 out (row-major [M,N])
// MODE 1: f32 out  (row-major [M,N])
// MODE 2: bf16 out transposed per batch: Vt[b*2048 + n][s], s = m % 2048
// MODE 3: bf16 out with fused RoPE (for Q/K projections)
template <int MODE, typename OutT>
__global__ __launch_bounds__(256) void gemm_bt(const u16* __restrict__ A,
                                               const u16* __restrict__ Bw,
                                               OutT* __restrict__ C,
                                               int M, int N, int K,
                                               const float* __restrict__ fc,
                                               const float* __restrict__ fs) {
  __shared__ __align__(16) u16 Al[128 * 32];
  __shared__ __align__(16) u16 Bl[128 * 32];
  const int tid  = threadIdx.x;
  const int wave = tid >> 6, lane = tid & 63;
  const int m0 = blockIdx.y * 128, n0 = blockIdx.x * 128;
  const int wr = (wave >> 1) * 64, wc = (wave & 1) * 64;
  const int lrow = lane & 15, lk = (lane >> 4) * 8;

  f32x4 acc[4][4] = {};

  for (int k0 = 0; k0 < K; k0 += 32) {
    __syncthreads();
#pragma unroll
    for (int i = 0; i < 2; ++i) {
      int idx = tid + i * 256;                 // 512 16B chunks per tile
      int row = idx >> 2, kc = (idx & 3) * 8;
      const u16* ga = A  + (size_t)(m0 + row) * K + k0 + kc;
      const u16* gb = Bw + (size_t)(n0 + row) * K + k0 + kc;
      __builtin_amdgcn_global_load_lds((const __attribute__((address_space(1))) u32*)ga,
                                       (__attribute__((address_space(3))) u32*)(Al + idx * 8),
                                       16, 0, 0);
      __builtin_amdgcn_global_load_lds((const __attribute__((address_space(1))) u32*)gb,
                                       (__attribute__((address_space(3))) u32*)(Bl + idx * 8),
                                       16, 0, 0);
    }
    __syncthreads();

    short8 af[4], bfr[4];
#pragma unroll
    for (int t = 0; t < 4; ++t) {
      af[t]  = *(const short8*)(Al + (wr + t * 16 + lrow) * 32 + lk);
      bfr[t] = *(const short8*)(Bl + (wc + t * 16 + lrow) * 32 + lk);
    }
#pragma unroll
    for (int mt = 0; mt < 4; ++mt)
#pragma unroll
      for (int nt = 0; nt < 4; ++nt)
        acc[mt][nt] = __builtin_amdgcn_mfma_f32_16x16x32_bf16(af[mt], bfr[nt], acc[mt][nt], 0, 0, 0);
  }

  const int dr = (lane >> 4) * 4;
#pragma unroll
  for (int mt = 0; mt < 4; ++mt)
#pragma unroll
    for (int nt = 0; nt < 4; ++nt) {
      if constexpr (MODE == 2) {
        int rr = m0 + wr + mt * 16 + dr;           // token index, multiple of 4
        int cc = n0 + wc + nt * 16 + lrow;         // h*128+d
        int b  = rr >> 11, s0 = rr & 2047;
        size_t vrow = (size_t)b * 2048 + cc;
        u16x4 pk;
#pragma unroll
        for (int i = 0; i < 4; ++i) pk[i] = f2bf(acc[mt][nt][i]);
        *(u16x4*)((u16*)C + vrow * 2048 + s0) = pk;
      } else if constexpr (MODE == 3) {
        // fused RoPE: pair partner value lives in lane^1 (col parity == lrow bit0)
        int c = n0 + wc + nt * 16 + lrow;
        int dh = c & 127, pi = dh >> 1;
        float sgn = (dh & 1) ? 1.f : -1.f;
#pragma unroll
        for (int i = 0; i < 4; ++i) {
          int r = m0 + wr + mt * 16 + dr + i;
          int s_ = r & (SS - 1);
          float cc_ = fc[s_ * 64 + pi];
          float ss_ = fs[s_ * 64 + pi];
          float v  = acc[mt][nt][i];
          float pv = __shfl_xor(v, 1, 64);
          ((u16*)C)[(size_t)r * N + c] = f2bf(v * cc_ + pv * (sgn * ss_));
        }
      } else {
#pragma unroll
        for (int i = 0; i < 4; ++i) {
          size_t r = (size_t)(m0 + wr + mt * 16 + dr + i);
          size_t cix = (size_t)(n0 + wc + nt * 16 + lrow);
          float v = acc[mt][nt][i];
          if constexpr (MODE == 0) ((u16*)C)[r * N + cix]  = f2bf(v);
          else                     ((float*)C)[r * N + cix] = v;
        }
      }
    }
}

// ---------------- Flash attention (causal), swapped 32x32 structure ----------------
// Q,K: bf16 [B*S, H*HD] (roped). Vt: bf16 [(b*H+h)*HD + d][s].
// Block: 4 waves, 128 Q-rows (32/wave). KV tiles of 64 keys, XOR-swizzled, dbuf.
// Grid: (bh=32, x=8); block x does q-tiles x and 15-x -> exactly 34 KV tiles.
__global__ __launch_bounds__(256, 1) void attn_kernel(const u16* __restrict__ Q,
                                                      const u16* __restrict__ K,
                                                      const u16* __restrict__ Vt,
                                                      u16* __restrict__ O) {
  __shared__ __align__(16) u16 Kl[2][64 * 128];   // [buf][key][d], swizzled
  __shared__ __align__(16) u16 Vl[2][128 * 64];   // [buf][d][key], swizzled
  __shared__ __align__(16) u16 Ot[4][32 * 128];   // per-wave O transpose scratch

  const int tid = threadIdx.x, wave = tid >> 6, lane = tid & 63;
  const int l31 = lane & 31, hi = lane >> 5;
  const int bh = blockIdx.x, b = bh >> 4, h = bh & 15;
  const int x = blockIdx.y;
  const size_t base    = ((size_t)b * SS) * DD + (size_t)h * HDD;
  const size_t vt_base = (size_t)bh * HDD * SS;
  const int swz = (l31 & 7) << 4;                 // byte-domain LDS read swizzle

#define STAGE(KT, BUF)                                                              \
  {                                                                                 \
    int k0s = (KT) * 64;                                                            \
    _Pragma("unroll")                                                               \
    for (int i_ = 0; i_ < 4; ++i_) {                                                \
      int idx = tid + i_ * 256;                                                     \
      int kr = idx >> 4, c_ = idx & 15;                                             \
      const u16* gk = K + base + (size_t)(k0s + kr) * DD + ((c_ ^ (kr & 7)) * 8);   \
      __builtin_amdgcn_global_load_lds((const __attribute__((address_space(1))) u32*)gk, \
                                       (__attribute__((address_space(3))) u32*)(&Kl[BUF][0] + idx * 8), \
                                       16, 0, 0);                                   \
      int dv = idx >> 3, c2 = idx & 7;                                              \
      const u16* gv = Vt + vt_base + (size_t)dv * SS + k0s + ((c2 ^ (dv & 7)) * 8); \
      __builtin_amdgcn_global_load_lds((const __attribute__((address_space(1))) u32*)gv, \
                                       (__attribute__((address_space(3))) u32*)(&Vl[BUF][0] + idx * 8), \
                                       16, 0, 0);                                   \
    }                                                                               \
  }

  int buf = 0;
  STAGE(0, 0);

  for (int qsel = 0; qsel < 2; ++qsel) {
    const int qt = qsel ? (15 - x) : x;
    const int qw = qt * 128 + wave * 32;
    const int q_ = qw + l31;

    // Q B-operand fragments: col=q (lane&31), k=d-chunk
    short8 qf[8];
#pragma unroll
    for (int kc = 0; kc < 8; ++kc)
      qf[kc] = *(const short8*)(Q + base + (size_t)(qw + l31) * DD + kc * 16 + hi * 8);

    f32x16 oacc[4] = {};
    float m_i = -1e30f, l_p = 0.f;

    const int ntiles = 2 * qt + 2;
    for (int kt = 0; kt < ntiles; ++kt) {
      const int k0 = kt * 64;
      const bool lastall = (qsel == 1) && (kt == ntiles - 1);
      if (!lastall) {
        int nk = (kt + 1 < ntiles) ? (kt + 1) : 0;   // cross-qsel prefetch of tile 0
        STAGE(nk, buf ^ 1);
        asm volatile("s_waitcnt vmcnt(8)" ::: "memory");
      } else {
        asm volatile("s_waitcnt vmcnt(0)" ::: "memory");
      }
      __syncthreads();

      if (k0 <= qw + 31) {                            // wave has unmasked keys in tile
        const u16* Kb_ = &Kl[buf][0];
        const u16* Vb_ = &Vl[buf][0];

        // S^T[key][q] = K * Q^T   (two 32-key blocks)
        f32x16 st[2] = {};
        __builtin_amdgcn_s_setprio(1);
#pragma unroll
        for (int kc = 0; kc < 8; ++kc) {
          int by0 = (l31 * 256)        + ((kc * 32 + hi * 16) ^ swz);
          int by1 = ((32 + l31) * 256) + ((kc * 32 + hi * 16) ^ swz);
          short8 a0 = *(const short8*)(Kb_ + (by0 >> 1));
          short8 a1 = *(const short8*)(Kb_ + (by1 >> 1));
          st[0] = __builtin_amdgcn_mfma_f32_32x32x16_bf16(a0, qf[kc], st[0], 0, 0, 0);
          st[1] = __builtin_amdgcn_mfma_f32_32x32x16_bf16(a1, qf[kc], st[1], 0, 0, 0);
        }
        __builtin_amdgcn_s_setprio(0);

        // scale (exp2 domain) + causal mask + row max (in-lane + partner)
        const float scale2 = 0.08838834764831845f * 1.44269504088896340736f;
        float mx = -1e30f;
#pragma unroll
        for (int kb = 0; kb < 2; ++kb)
#pragma unroll
          for (int r = 0; r < 16; ++r) {
            float s = st[kb][r] * scale2;
            int key = k0 + kb * 32 + (r & 3) + ((r >> 2) << 3) + (hi << 2);
            if (key > q_) s = -1e30f;
            st[kb][r] = s;
            mx = fmaxf(mx, s);
          }
        mx = fmaxf(mx, __shfl_xor(mx, 32, 64));

        // defer-max (T13): rescale only when running max grows by > 8 (exp2 dom.)
        if (__any(mx > m_i + 8.f)) {
          float mn  = fmaxf(m_i, mx);
          float esc = exp2f(m_i - mn);
          m_i = mn; l_p *= esc;
#pragma unroll
          for (int db = 0; db < 4; ++db)
#pragma unroll
            for (int r = 0; r < 16; ++r) oacc[db][r] *= esc;
        }
        float sum = 0.f;
#pragma unroll
        for (int kb = 0; kb < 2; ++kb)
#pragma unroll
          for (int r = 0; r < 16; ++r) {
            float e = exp2f(st[kb][r] - m_i);
            st[kb][r] = e;
            sum += e;
          }
        l_p += sum;

        // P pack (cvt_pk + permlane32_swap) and PV: O^T += V^T * P^T
        __builtin_amdgcn_s_setprio(1);
#pragma unroll
        for (int kb = 0; kb < 2; ++kb) {
#pragma unroll
          for (int half = 0; half < 2; ++half) {     // regs 0-7 / 8-15 -> kt sub 0/1
            const int rb = half * 8;
            u32 w0 = cvtpk(st[kb][rb + 0], st[kb][rb + 1]);
            u32 w1 = cvtpk(st[kb][rb + 2], st[kb][rb + 3]);
            u32 w2 = cvtpk(st[kb][rb + 4], st[kb][rb + 5]);
            u32 w3 = cvtpk(st[kb][rb + 6], st[kb][rb + 7]);
            permswap(w0, w2);                        // w0->word0, w2->word2
            permswap(w1, w3);                        // w1->word1, w3->word3
            short8 pf = __builtin_bit_cast(short8, (u32x4){w0, w1, w2, w3});
            const int ktv = kb * 2 + half;           // 16-key chunk index
#pragma unroll
            for (int db = 0; db < 4; ++db) {
              int d = db * 32 + l31;
              int by = d * 128 + ((ktv * 32 + hi * 16) ^ swz);
              short8 vf = *(const short8*)(Vb_ + (by >> 1));
              oacc[db] = __builtin_amdgcn_mfma_f32_32x32x16_bf16(vf, pf, oacc[db], 0, 0, 0);
            }
          }
        }
        __builtin_amdgcn_s_setprio(0);
      }
      __syncthreads();                // reads of buf done before it is restaged
      buf ^= 1;
    }

    // epilogue: combine partner l, normalize, transpose via LDS, coalesced store
    float lt  = l_p + __shfl_xor(l_p, 32, 64);
    float inv = 1.f / lt;
    u16* ow = &Ot[wave][0];
#pragma unroll
    for (int db = 0; db < 4; ++db)
#pragma unroll
      for (int i = 0; i < 8; ++i) {
        // pair of consecutive d: d_even = db*32 + (i&1)*2 + (i>>1)*8 + 4*hi
        int deven = db * 32 + (i & 1) * 2 + ((i >> 1) << 3) + (hi << 2);
        int c  = deven >> 1;
        int cs = c ^ ((l31 & 7) << 2);               // dword swizzle (chunk ^ q&7)
        u32 pk = cvtpk(oacc[db][2 * i] * inv, oacc[db][2 * i + 1] * inv);
        *(u32*)(ow + l31 * 128 + cs * 2) = pk;
      }
    // read back rows, store coalesced (lanes 0-15 cover one row's 256B)
#pragma unroll
    for (int ps = 0; ps < 8; ++ps) {
      int qr  = ps * 4 + (lane >> 4);
      int ch  = lane & 15;
      int chs = ch ^ (qr & 7);
      short8 ov = *(const short8*)(ow + qr * 128 + chs * 8);
      *(short8*)(O + base + (size_t)(qw + qr) * DD + ch * 8) = ov;
    }
  }
#undef STAGE
}

// ---------------- launcher ----------------
extern "C" void kernel_launch(void* const* d_in, const int* in_sizes, int n_in,
                              void* d_out, int out_size, void* d_ws, size_t ws_size,
                              hipStream_t stream) {
  (void)in_sizes; (void)n_in; (void)out_size; (void)ws_size;
  const float* x  = (const float*)d_in[0];
  const float* wq = (const float*)d_in[1];
  const float* wk = (const float*)d_in[2];
  const float* wv = (const float*)d_in[3];
  const float* wo = (const float*)d_in[4];
  const float* fc = (const float*)d_in[5];
  const float* fs = (const float*)d_in[6];
  float* out = (float*)d_out;

  const size_t BUF = 16777216;  // M*D * 2 bytes = D*D * 2 bytes
  char* ws = (char*)d_ws;
  u16* xb  = (u16*)(ws + 0 * BUF);   // also reused as O (attention output)
  u16* wqb = (u16*)(ws + 1 * BUF);   // also reused as Vt (post-projection, transposed)
  u16* wkb = (u16*)(ws + 2 * BUF);
  u16* wvb = (u16*)(ws + 3 * BUF);
  u16* wob = (u16*)(ws + 4 * BUF);
  u16* Qb  = (u16*)(ws + 5 * BUF);
  u16* Kb  = (u16*)(ws + 6 * BUF);
  u16* Vtb = wqb;
  u16* Ob  = xb;

  const int ncv = (MM * DD) / 4 + 4 * ((DD * DD) / 4);   // 6291456
  cvt_all<<<ncv / 256, 256, 0, stream>>>(x, wq, wk, wv, wo, xb, wqb, wkb, wvb, wob);

  dim3 gg(DD / 128, MM / 128);       // (16, 32)
  gemm_bt<3, u16><<<gg, 256, 0, stream>>>(xb, wqb, Qb, MM, DD, DD, fc, fs);
  gemm_bt<3, u16><<<gg, 256, 0, stream>>>(xb, wkb, Kb, MM, DD, DD, fc, fs);
  gemm_bt<2, u16><<<gg, 256, 0, stream>>>(xb, wvb, Vtb, MM, DD, DD, fc, fs);

  attn_kernel<<<dim3(32, 8), 256, 0, stream>>>(Qb, Kb, Vtb, Ob);

  gemm_bt<1, float><<<gg, 256, 0, stream>>>(Ob, wob, out, MM, DD, DD, fc, fs);
}

// Round 5
// 329.002 us; speedup vs baseline: 2.3608x; 1.0177x over previous
//
#include <hip/hip_runtime.h>
#include <stdint.h>

// Problem: B=2, S=2048, D=2048, H=16, HD=128, M = B*S = 4096
#define BB  2
#define SS  2048
#define DD  2048
#define HH  16
#define HDD 128
#define MM  (BB * SS)

typedef __attribute__((ext_vector_type(8)))  short short8;
typedef __attribute__((ext_vector_type(4)))  float f32x4;
typedef __attribute__((ext_vector_type(16))) float f32x16;
typedef unsigned int   u32;
typedef unsigned short u16;
typedef __attribute__((ext_vector_type(4))) u16 u16x4;
typedef __attribute__((ext_vector_type(2))) u32 u32x2;
typedef __attribute__((ext_vector_type(4))) u32 u32x4;

static __device__ __forceinline__ u16 f2bf(float f) {
  u32 u = __builtin_bit_cast(u32, f);
  u32 r = u + 0x7fffu + ((u >> 16) & 1u);
  return (u16)(r >> 16);
}

static __device__ __forceinline__ u32 cvtpk(float a, float b) {
  u32 r;
  asm("v_cvt_pk_bf16_f32 %0, %1, %2" : "=v"(r) : "v"(a), "v"(b));
  return r;
}
static __device__ __forceinline__ void permswap(u32& a, u32& b) {
  asm volatile("v_permlane32_swap_b32 %0, %1" : "+v"(a), "+v"(b));
}

// ---------------- fused fp32 -> bf16 conversion for all 5 tensors ----------------
__global__ void cvt_all(const float* __restrict__ x,  const float* __restrict__ wq,
                        const float* __restrict__ wk, const float* __restrict__ wv,
                        const float* __restrict__ wo,
                        u16* __restrict__ xb,  u16* __restrict__ wqb,
                        u16* __restrict__ wkb, u16* __restrict__ wvb,
                        u16* __restrict__ wob) {
  const int NX = (MM * DD) / 4;        // 2097152 chunks for x
  const int NW = (DD * DD) / 4;        // 1048576 chunks per weight
  int i = blockIdx.x * blockDim.x + threadIdx.x;
  const float* s; u16* d; int off;
  if (i < NX) { s = x; d = xb; off = i; }
  else {
    int j = i - NX; int w = j >> 20; off = j & (NW - 1);
    s = (w == 0) ? wq : (w == 1) ? wk : (w == 2) ? wv : wo;
    d = (w == 0) ? wqb : (w == 1) ? wkb : (w == 2) ? wvb : wob;
  }
  f32x4 v = *(const f32x4*)(s + (size_t)off * 4);
  u16x4 o;
#pragma unroll
  for (int j = 0; j < 4; ++j) o[j] = f2bf(v[j]);
  *(u16x4*)(d + (size_t)off * 4) = o;
}

// ---------------- GEMM: C[M,N] = A[M,K] * B[N,K]^T ----------------
// MODE 0: bf16 out (row-major [M,N])
// MODE 1: f32 out  (row-major [M,N])
// MODE 2: bf16 out transposed per batch: Vt[b*2048 + n][s], s = m % 2048
// MODE 3: bf16 out with fused RoPE (for Q/K projections)
template <int MODE, typename OutT>
__global__ __launch_bounds__(256) void gemm_bt(const u16* __restrict__ A,
                                               const u16* __restrict__ Bw,
                                               OutT* __restrict__ C,
                                               int M, int N, int K,
                                               const float* __restrict__ fc,
                                               const float* __restrict__ fs) {
  __shared__ __align__(16) u16 Al[128 * 32];
  __shared__ __align__(16) u16 Bl[128 * 32];
  const int tid  = threadIdx.x;
  const int wave = tid >> 6, lane = tid & 63;
  const int m0 = blockIdx.y * 128, n0 = blockIdx.x * 128;
  const int wr = (wave >> 1) * 64, wc = (wave & 1) * 64;
  const int lrow = lane & 15, lk = (lane >> 4) * 8;

  f32x4 acc[4][4] = {};

  for (int k0 = 0; k0 < K; k0 += 32) {
    __syncthreads();
#pragma unroll
    for (int i = 0; i < 2; ++i) {
      int idx = tid + i * 256;                 // 512 16B chunks per tile
      int row = idx >> 2, kc = (idx & 3) * 8;
      const u16* ga = A  + (size_t)(m0 + row) * K + k0 + kc;
      const u16* gb = Bw + (size_t)(n0 + row) * K + k0 + kc;
      __builtin_amdgcn_global_load_lds((const __attribute__((address_space(1))) u32*)ga,
                                       (__attribute__((address_space(3))) u32*)(Al + idx * 8),
                                       16, 0, 0);
      __builtin_amdgcn_global_load_lds((const __attribute__((address_space(1))) u32*)gb,
                                       (__attribute__((address_space(3))) u32*)(Bl + idx * 8),
                                       16, 0, 0);
    }
    __syncthreads();

    short8 af[4], bfr[4];
#pragma unroll
    for (int t = 0; t < 4; ++t) {
      af[t]  = *(const short8*)(Al + (wr + t * 16 + lrow) * 32 + lk);
      bfr[t] = *(const short8*)(Bl + (wc + t * 16 + lrow) * 32 + lk);
    }
#pragma unroll
    for (int mt = 0; mt < 4; ++mt)
#pragma unroll
      for (int nt = 0; nt < 4; ++nt)
        acc[mt][nt] = __builtin_amdgcn_mfma_f32_16x16x32_bf16(af[mt], bfr[nt], acc[mt][nt], 0, 0, 0);
  }

  const int dr = (lane >> 4) * 4;
#pragma unroll
  for (int mt = 0; mt < 4; ++mt)
#pragma unroll
    for (int nt = 0; nt < 4; ++nt) {
      if constexpr (MODE == 2) {
        int rr = m0 + wr + mt * 16 + dr;           // token index, multiple of 4
        int cc = n0 + wc + nt * 16 + lrow;         // h*128+d
        int b  = rr >> 11, s0 = rr & 2047;
        size_t vrow = (size_t)b * 2048 + cc;
        u16x4 pk;
#pragma unroll
        for (int i = 0; i < 4; ++i) pk[i] = f2bf(acc[mt][nt][i]);
        *(u16x4*)((u16*)C + vrow * 2048 + s0) = pk;
      } else if constexpr (MODE == 3) {
        // fused RoPE: pair partner value lives in lane^1 (col parity == lrow bit0)
        int c = n0 + wc + nt * 16 + lrow;
        int dh = c & 127, pi = dh >> 1;
        float sgn = (dh & 1) ? 1.f : -1.f;
#pragma unroll
        for (int i = 0; i < 4; ++i) {
          int r = m0 + wr + mt * 16 + dr + i;
          int s_ = r & (SS - 1);
          float cc_ = fc[s_ * 64 + pi];
          float ss_ = fs[s_ * 64 + pi];
          float v  = acc[mt][nt][i];
          float pv = __shfl_xor(v, 1, 64);
          ((u16*)C)[(size_t)r * N + c] = f2bf(v * cc_ + pv * (sgn * ss_));
        }
      } else {
#pragma unroll
        for (int i = 0; i < 4; ++i) {
          size_t r = (size_t)(m0 + wr + mt * 16 + dr + i);
          size_t cix = (size_t)(n0 + wc + nt * 16 + lrow);
          float v = acc[mt][nt][i];
          if constexpr (MODE == 0) ((u16*)C)[r * N + cix]  = f2bf(v);
          else                     ((float*)C)[r * N + cix] = v;
        }
      }
    }
}

// ---------------- Flash attention (causal), swapped 32x32, 2 blocks/CU ----------------
// Q,K: bf16 [B*S, H*HD] (roped). Vt: bf16 [(b*H+h)*HD + d][s].
// Block: 4 waves, ONE 128-row q-tile (32 rows/wave). KV tiles of 64 keys, dbuf.
// Grid (bh=32, y=16): qt = y<8 ? y : 23-y, so co-resident pair (i, i+256) sums
// to 34 KV tiles on every CU; x=bh keeps each head's KV on one XCD.
__global__ __launch_bounds__(256, 2) void attn_kernel(const u16* __restrict__ Q,
                                                      const u16* __restrict__ K,
                                                      const u16* __restrict__ Vt,
                                                      u16* __restrict__ O) {
  __shared__ __align__(16) u16 Kl[2][64 * 128];   // [buf][key][d], swizzled
  __shared__ __align__(16) u16 Vl[2][128 * 64];   // [buf][d][key], swizzled

  const int tid = threadIdx.x, wave = tid >> 6, lane = tid & 63;
  const int l31 = lane & 31, hi = lane >> 5;
  const int bh = blockIdx.x, b = bh >> 4, h = bh & 15;
  const int y = blockIdx.y;
  const int qt = (y < 8) ? y : (23 - y);
  const size_t base    = ((size_t)b * SS) * DD + (size_t)h * HDD;
  const size_t vt_base = (size_t)bh * HDD * SS;
  const int swz = (l31 & 7) << 4;                 // byte-domain LDS read swizzle

#define STAGE(KT, BUF)                                                              \
  {                                                                                 \
    int k0s = (KT) * 64;                                                            \
    _Pragma("unroll")                                                               \
    for (int i_ = 0; i_ < 4; ++i_) {                                                \
      int idx = tid + i_ * 256;                                                     \
      int kr = idx >> 4, c_ = idx & 15;                                             \
      const u16* gk = K + base + (size_t)(k0s + kr) * DD + ((c_ ^ (kr & 7)) * 8);   \
      __builtin_amdgcn_global_load_lds((const __attribute__((address_space(1))) u32*)gk, \
                                       (__attribute__((address_space(3))) u32*)(&Kl[BUF][0] + idx * 8), \
                                       16, 0, 0);                                   \
      int dv = idx >> 3, c2 = idx & 7;                                              \
      const u16* gv = Vt + vt_base + (size_t)dv * SS + k0s + ((c2 ^ (dv & 7)) * 8); \
      __builtin_amdgcn_global_load_lds((const __attribute__((address_space(1))) u32*)gv, \
                                       (__attribute__((address_space(3))) u32*)(&Vl[BUF][0] + idx * 8), \
                                       16, 0, 0);                                   \
    }                                                                               \
  }

  const int qw = qt * 128 + wave * 32;
  const int q_ = qw + l31;

  // Q B-operand fragments: col=q (lane&31), k=d-chunk
  short8 qf[8];
#pragma unroll
  for (int kc = 0; kc < 8; ++kc)
    qf[kc] = *(const short8*)(Q + base + (size_t)(qw + l31) * DD + kc * 16 + hi * 8);

  f32x16 oacc[4] = {};
  float m_i = -1e30f, l_p = 0.f;

  int buf = 0;
  STAGE(0, 0);

  const int ntiles = 2 * qt + 2;
  for (int kt = 0; kt < ntiles; ++kt) {
    const int k0 = kt * 64;
    if (kt + 1 < ntiles) {
      STAGE(kt + 1, buf ^ 1);
      asm volatile("s_waitcnt vmcnt(8)" ::: "memory");
    } else {
      asm volatile("s_waitcnt vmcnt(0)" ::: "memory");
    }
    __syncthreads();

    if (k0 <= qw + 31) {                            // wave has unmasked keys in tile
      const u16* Kb_ = &Kl[buf][0];
      const u16* Vb_ = &Vl[buf][0];

      // S^T[key][q] = K * Q^T   (two 32-key blocks)
      f32x16 st[2] = {};
      __builtin_amdgcn_s_setprio(1);
#pragma unroll
      for (int kc = 0; kc < 8; ++kc) {
        int by0 = (l31 * 256)        + ((kc * 32 + hi * 16) ^ swz);
        int by1 = ((32 + l31) * 256) + ((kc * 32 + hi * 16) ^ swz);
        short8 a0 = *(const short8*)(Kb_ + (by0 >> 1));
        short8 a1 = *(const short8*)(Kb_ + (by1 >> 1));
        st[0] = __builtin_amdgcn_mfma_f32_32x32x16_bf16(a0, qf[kc], st[0], 0, 0, 0);
        st[1] = __builtin_amdgcn_mfma_f32_32x32x16_bf16(a1, qf[kc], st[1], 0, 0, 0);
      }
      __builtin_amdgcn_s_setprio(0);

      // scale (exp2 domain) + causal mask + row max (in-lane + partner)
      const float scale2 = 0.08838834764831845f * 1.44269504088896340736f;
      float mx = -1e30f;
#pragma unroll
      for (int kb = 0; kb < 2; ++kb)
#pragma unroll
        for (int r = 0; r < 16; ++r) {
          float s = st[kb][r] * scale2;
          int key = k0 + kb * 32 + (r & 3) + ((r >> 2) << 3) + (hi << 2);
          if (key > q_) s = -1e30f;
          st[kb][r] = s;
          mx = fmaxf(mx, s);
        }
      mx = fmaxf(mx, __shfl_xor(mx, 32, 64));

      // defer-max (T13): rescale only when running max grows by > 8 (exp2 dom.)
      if (__any(mx > m_i + 8.f)) {
        float mn  = fmaxf(m_i, mx);
        float esc = exp2f(m_i - mn);
        m_i = mn; l_p *= esc;
#pragma unroll
        for (int db = 0; db < 4; ++db)
#pragma unroll
          for (int r = 0; r < 16; ++r) oacc[db][r] *= esc;
      }
      float sum = 0.f;
#pragma unroll
      for (int kb = 0; kb < 2; ++kb)
#pragma unroll
        for (int r = 0; r < 16; ++r) {
          float e = exp2f(st[kb][r] - m_i);
          st[kb][r] = e;
          sum += e;
        }
      l_p += sum;

      // P pack (cvt_pk + permlane32_swap) and PV: O^T += V^T * P^T
      __builtin_amdgcn_s_setprio(1);
#pragma unroll
      for (int kb = 0; kb < 2; ++kb) {
#pragma unroll
        for (int half = 0; half < 2; ++half) {     // regs 0-7 / 8-15 -> kt sub 0/1
          const int rb = half * 8;
          u32 w0 = cvtpk(st[kb][rb + 0], st[kb][rb + 1]);
          u32 w1 = cvtpk(st[kb][rb + 2], st[kb][rb + 3]);
          u32 w2 = cvtpk(st[kb][rb + 4], st[kb][rb + 5]);
          u32 w3 = cvtpk(st[kb][rb + 6], st[kb][rb + 7]);
          permswap(w0, w2);                        // w0->word0, w2->word2
          permswap(w1, w3);                        // w1->word1, w3->word3
          short8 pf = __builtin_bit_cast(short8, (u32x4){w0, w1, w2, w3});
          const int ktv = kb * 2 + half;           // 16-key chunk index
#pragma unroll
          for (int db = 0; db < 4; ++db) {
            int d = db * 32 + l31;
            int by = d * 128 + ((ktv * 32 + hi * 16) ^ swz);
            short8 vf = *(const short8*)(Vb_ + (by >> 1));
            oacc[db] = __builtin_amdgcn_mfma_f32_32x32x16_bf16(vf, pf, oacc[db], 0, 0, 0);
          }
        }
      }
      __builtin_amdgcn_s_setprio(0);
    }
    __syncthreads();                // reads of buf done before it is restaged
    buf ^= 1;
  }

  // epilogue: combine partner l, normalize, direct packed stores.
  // Regs 4g..4g+3 of oacc[db] hold 4 consecutive d = db*32 + 8g + 4hi + {0..3};
  // lane row = qw + l31. 8B stores; the 8 instrs covering a 64B sector are
  // back-to-back so L2 write-combines them.
  float lt  = l_p + __shfl_xor(l_p, 32, 64);
  float inv = 1.f / lt;
#pragma unroll
  for (int db = 0; db < 4; ++db)
#pragma unroll
    for (int g = 0; g < 4; ++g) {
      int d0 = db * 32 + 8 * g + 4 * hi;
      u32x2 pk;
      pk[0] = cvtpk(oacc[db][4 * g + 0] * inv, oacc[db][4 * g + 1] * inv);
      pk[1] = cvtpk(oacc[db][4 * g + 2] * inv, oacc[db][4 * g + 3] * inv);
      *(u32x2*)(O + base + (size_t)q_ * DD + d0) = pk;
    }
#undef STAGE
}

// ---------------- launcher ----------------
extern "C" void kernel_launch(void* const* d_in, const int* in_sizes, int n_in,
                              void* d_out, int out_size, void* d_ws, size_t ws_size,
                              hipStream_t stream) {
  (void)in_sizes; (void)n_in; (void)out_size; (void)ws_size;
  const float* x  = (const float*)d_in[0];
  const float* wq = (const float*)d_in[1];
  const float* wk = (const float*)d_in[2];
  const float* wv = (const float*)d_in[3];
  const float* wo = (const float*)d_in[4];
  const float* fc = (const float*)d_in[5];
  const float* fs = (const float*)d_in[6];
  float* out = (float*)d_out;

  const size_t BUF = 16777216;  // M*D * 2 bytes = D*D * 2 bytes
  char* ws = (char*)d_ws;
  u16* xb  = (u16*)(ws + 0 * BUF);   // also reused as O (attention output)
  u16* wqb = (u16*)(ws + 1 * BUF);   // also reused as Vt (post-projection, transposed)
  u16* wkb = (u16*)(ws + 2 * BUF);
  u16* wvb = (u16*)(ws + 3 * BUF);
  u16* wob = (u16*)(ws + 4 * BUF);
  u16* Qb  = (u16*)(ws + 5 * BUF);
  u16* Kb  = (u16*)(ws + 6 * BUF);
  u16* Vtb = wqb;
  u16* Ob  = xb;

  const int ncv = (MM * DD) / 4 + 4 * ((DD * DD) / 4);   // 6291456
  cvt_all<<<ncv / 256, 256, 0, stream>>>(x, wq, wk, wv, wo, xb, wqb, wkb, wvb, wob);

  dim3 gg(DD / 128, MM / 128);       // (16, 32)
  gemm_bt<3, u16><<<gg, 256, 0, stream>>>(xb, wqb, Qb, MM, DD, DD, fc, fs);
  gemm_bt<3, u16><<<gg, 256, 0, stream>>>(xb, wkb, Kb, MM, DD, DD, fc, fs);
  gemm_bt<2, u16><<<gg, 256, 0, stream>>>(xb, wvb, Vtb, MM, DD, DD, fc, fs);

  attn_kernel<<<dim3(32, 16), 256, 0, stream>>>(Qb, Kb, Vtb, Ob);

  gemm_bt<1, float><<<gg, 256, 0, stream>>>(Ob, wob, out, MM, DD, DD, fc, fs);
}

// Round 6
// 275.760 us; speedup vs baseline: 2.8167x; 1.1931x over previous
//
#include <hip/hip_runtime.h>
#include <stdint.h>

// Problem: B=2, S=2048, D=2048, H=16, HD=128, M = B*S = 4096
#define BB  2
#define SS  2048
#define DD  2048
#define HH  16
#define HDD 128
#define MM  (BB * SS)

typedef __attribute__((ext_vector_type(8)))  short short8;
typedef __attribute__((ext_vector_type(4)))  float f32x4;
typedef __attribute__((ext_vector_type(16))) float f32x16;
typedef unsigned int   u32;
typedef unsigned short u16;
typedef __attribute__((ext_vector_type(4))) u16 u16x4;
typedef __attribute__((ext_vector_type(2))) u32 u32x2;
typedef __attribute__((ext_vector_type(4))) u32 u32x4;

static __device__ __forceinline__ u16 f2bf(float f) {
  u32 u = __builtin_bit_cast(u32, f);
  u32 r = u + 0x7fffu + ((u >> 16) & 1u);
  return (u16)(r >> 16);
}

static __device__ __forceinline__ u32 cvtpk(float a, float b) {
  u32 r;
  asm("v_cvt_pk_bf16_f32 %0, %1, %2" : "=v"(r) : "v"(a), "v"(b));
  return r;
}
static __device__ __forceinline__ void permswap(u32& a, u32& b) {
  asm volatile("v_permlane32_swap_b32 %0, %1" : "+v"(a), "+v"(b));
}

// ---------------- fused fp32 -> bf16 conversion for all 5 tensors ----------------
// Weights wq/wk/wv go CONTIGUOUSLY into wqkv[6144][2048]; wo separate.
__global__ void cvt_all(const float* __restrict__ x,  const float* __restrict__ wq,
                        const float* __restrict__ wk, const float* __restrict__ wv,
                        const float* __restrict__ wo,
                        u16* __restrict__ xb, u16* __restrict__ wqkv,
                        u16* __restrict__ wob) {
  const int NX = (MM * DD) / 4;        // 2097152 chunks for x
  const int NW = (DD * DD) / 4;        // 1048576 chunks per weight
  int i = blockIdx.x * blockDim.x + threadIdx.x;
  const float* s; u16* d; int off;
  if (i < NX) { s = x; d = xb; off = i; }
  else {
    int j = i - NX; int w = j >> 20; off = j & (NW - 1);
    s = (w == 0) ? wq : (w == 1) ? wk : (w == 2) ? wv : wo;
    d = (w < 3) ? (wqkv + (size_t)w * DD * DD) : wob;
  }
  f32x4 v = *(const f32x4*)(s + (size_t)off * 4);
  u16x4 o;
#pragma unroll
  for (int j = 0; j < 4; ++j) o[j] = f2bf(v[j]);
  *(u16x4*)(d + (size_t)off * 4) = o;
}

// ---------------- GEMM: C[M,N] = A[M,K] * B[N,K]^T, 3-buf pipelined ----------------
// One barrier per K-step; counted vmcnt keeps next tile's loads in flight.
// MODE 1: f32 out row-major (O-projection)
// MODE 4: QKV fused epilogue — n<2048: rope->Cq; n<4096: rope->Ck; else V-transpose->Cvt
template <int MODE>
__global__ __launch_bounds__(256) void gemm2(const u16* __restrict__ A,
                                             const u16* __restrict__ Bw,
                                             u16* __restrict__ Cq,
                                             u16* __restrict__ Ck,
                                             u16* __restrict__ Cvt,
                                             float* __restrict__ Cf,
                                             int M, int N, int K,
                                             const float* __restrict__ fc,
                                             const float* __restrict__ fs) {
  __shared__ __align__(16) u16 Al[3][128 * 32];
  __shared__ __align__(16) u16 Bl[3][128 * 32];
  const int tid  = threadIdx.x;
  const int wave = tid >> 6, lane = tid & 63;
  const int m0 = blockIdx.y * 128, n0 = blockIdx.x * 128;
  const int wr = (wave >> 1) * 64, wc = (wave & 1) * 64;
  const int lrow = lane & 15, lk = (lane >> 4) * 8;

  f32x4 acc[4][4] = {};

#define GSTAGE(T, BUF)                                                                  \
  {                                                                                     \
    int koff = (T) * 32;                                                                \
    _Pragma("unroll")                                                                   \
    for (int i_ = 0; i_ < 2; ++i_) {                                                    \
      int idx = tid + i_ * 256;                                                         \
      int row = idx >> 2, kc = (idx & 3) * 8;                                           \
      const u16* ga = A  + (size_t)(m0 + row) * K + koff + kc;                          \
      const u16* gb = Bw + (size_t)(n0 + row) * K + koff + kc;                          \
      __builtin_amdgcn_global_load_lds((const __attribute__((address_space(1))) u32*)ga,\
                                       (__attribute__((address_space(3))) u32*)(&Al[BUF][0] + idx * 8), \
                                       16, 0, 0);                                       \
      __builtin_amdgcn_global_load_lds((const __attribute__((address_space(1))) u32*)gb,\
                                       (__attribute__((address_space(3))) u32*)(&Bl[BUF][0] + idx * 8), \
                                       16, 0, 0);                                       \
    }                                                                                   \
  }

  const int NT = K / 32;               // 64
  GSTAGE(0, 0);
  int cur = 0;
  for (int t = 0; t < NT; ++t) {
    int nxt = cur + 1; if (nxt == 3) nxt = 0;
    if (t + 1 < NT) {
      GSTAGE(t + 1, nxt);
      asm volatile("s_waitcnt vmcnt(4)" ::: "memory");   // tile t complete; t+1 in flight
    } else {
      asm volatile("s_waitcnt vmcnt(0)" ::: "memory");
    }
    __syncthreads();

    const u16* Ab = &Al[cur][0];
    const u16* Bb = &Bl[cur][0];
    short8 af[4], bfr[4];
#pragma unroll
    for (int tt = 0; tt < 4; ++tt) {
      af[tt]  = *(const short8*)(Ab + (wr + tt * 16 + lrow) * 32 + lk);
      bfr[tt] = *(const short8*)(Bb + (wc + tt * 16 + lrow) * 32 + lk);
    }
#pragma unroll
    for (int mt = 0; mt < 4; ++mt)
#pragma unroll
      for (int nt = 0; nt < 4; ++nt)
        acc[mt][nt] = __builtin_amdgcn_mfma_f32_16x16x32_bf16(af[mt], bfr[nt], acc[mt][nt], 0, 0, 0);
    cur = nxt;
  }
#undef GSTAGE

  const int dr = (lane >> 4) * 4;
  if constexpr (MODE == 1) {
#pragma unroll
    for (int mt = 0; mt < 4; ++mt)
#pragma unroll
      for (int nt = 0; nt < 4; ++nt)
#pragma unroll
        for (int i = 0; i < 4; ++i) {
          size_t r = (size_t)(m0 + wr + mt * 16 + dr + i);
          size_t c = (size_t)(n0 + wc + nt * 16 + lrow);
          Cf[r * N + c] = acc[mt][nt][i];
        }
  } else {
    const int region = n0 >> 11;        // 0:Q 1:K 2:V  (block-uniform)
    if (region < 2) {
      u16* Cd = region ? Ck : Cq;
#pragma unroll
      for (int mt = 0; mt < 4; ++mt)
#pragma unroll
        for (int nt = 0; nt < 4; ++nt) {
          int c  = n0 + wc + nt * 16 + lrow;
          int cl = c & 2047;
          int dh = cl & 127, pi = dh >> 1;
          float sgn = (dh & 1) ? 1.f : -1.f;
#pragma unroll
          for (int i = 0; i < 4; ++i) {
            int r  = m0 + wr + mt * 16 + dr + i;
            int s_ = r & (SS - 1);
            float v  = acc[mt][nt][i];
            float pv = __shfl_xor(v, 1, 64);
            Cd[(size_t)r * 2048 + cl] = f2bf(v * fc[s_ * 64 + pi] + pv * (sgn * fs[s_ * 64 + pi]));
          }
        }
    } else {
#pragma unroll
      for (int mt = 0; mt < 4; ++mt)
#pragma unroll
        for (int nt = 0; nt < 4; ++nt) {
          int cl = (n0 - 4096) + wc + nt * 16 + lrow;   // h*128+d
          int rr = m0 + wr + mt * 16 + dr;              // token, multiple of 4
          int b  = rr >> 11, s0 = rr & 2047;
          u16x4 pk;
#pragma unroll
          for (int i = 0; i < 4; ++i) pk[i] = f2bf(acc[mt][nt][i]);
          *(u16x4*)(Cvt + ((size_t)b * 2048 + cl) * 2048 + s0) = pk;
        }
    }
  }
}

// ---------------- Flash attention (causal), swapped 32x32, 2 blocks/CU ----------------
// (unchanged from previous round)
__global__ __launch_bounds__(256, 2) void attn_kernel(const u16* __restrict__ Q,
                                                      const u16* __restrict__ K,
                                                      const u16* __restrict__ Vt,
                                                      u16* __restrict__ O) {
  __shared__ __align__(16) u16 Kl[2][64 * 128];   // [buf][key][d], swizzled
  __shared__ __align__(16) u16 Vl[2][128 * 64];   // [buf][d][key], swizzled

  const int tid = threadIdx.x, wave = tid >> 6, lane = tid & 63;
  const int l31 = lane & 31, hi = lane >> 5;
  const int bh = blockIdx.x, b = bh >> 4, h = bh & 15;
  const int y = blockIdx.y;
  const int qt = (y < 8) ? y : (23 - y);
  const size_t base    = ((size_t)b * SS) * DD + (size_t)h * HDD;
  const size_t vt_base = (size_t)bh * HDD * SS;
  const int swz = (l31 & 7) << 4;                 // byte-domain LDS read swizzle

#define STAGE(KT, BUF)                                                              \
  {                                                                                 \
    int k0s = (KT) * 64;                                                            \
    _Pragma("unroll")                                                               \
    for (int i_ = 0; i_ < 4; ++i_) {                                                \
      int idx = tid + i_ * 256;                                                     \
      int kr = idx >> 4, c_ = idx & 15;                                             \
      const u16* gk = K + base + (size_t)(k0s + kr) * DD + ((c_ ^ (kr & 7)) * 8);   \
      __builtin_amdgcn_global_load_lds((const __attribute__((address_space(1))) u32*)gk, \
                                       (__attribute__((address_space(3))) u32*)(&Kl[BUF][0] + idx * 8), \
                                       16, 0, 0);                                   \
      int dv = idx >> 3, c2 = idx & 7;                                              \
      const u16* gv = Vt + vt_base + (size_t)dv * SS + k0s + ((c2 ^ (dv & 7)) * 8); \
      __builtin_amdgcn_global_load_lds((const __attribute__((address_space(1))) u32*)gv, \
                                       (__attribute__((address_space(3))) u32*)(&Vl[BUF][0] + idx * 8), \
                                       16, 0, 0);                                   \
    }                                                                               \
  }

  const int qw = qt * 128 + wave * 32;
  const int q_ = qw + l31;

  short8 qf[8];
#pragma unroll
  for (int kc = 0; kc < 8; ++kc)
    qf[kc] = *(const short8*)(Q + base + (size_t)(qw + l31) * DD + kc * 16 + hi * 8);

  f32x16 oacc[4] = {};
  float m_i = -1e30f, l_p = 0.f;

  int buf = 0;
  STAGE(0, 0);

  const int ntiles = 2 * qt + 2;
  for (int kt = 0; kt < ntiles; ++kt) {
    const int k0 = kt * 64;
    if (kt + 1 < ntiles) {
      STAGE(kt + 1, buf ^ 1);
      asm volatile("s_waitcnt vmcnt(8)" ::: "memory");
    } else {
      asm volatile("s_waitcnt vmcnt(0)" ::: "memory");
    }
    __syncthreads();

    if (k0 <= qw + 31) {
      const u16* Kb_ = &Kl[buf][0];
      const u16* Vb_ = &Vl[buf][0];

      f32x16 st[2] = {};
      __builtin_amdgcn_s_setprio(1);
#pragma unroll
      for (int kc = 0; kc < 8; ++kc) {
        int by0 = (l31 * 256)        + ((kc * 32 + hi * 16) ^ swz);
        int by1 = ((32 + l31) * 256) + ((kc * 32 + hi * 16) ^ swz);
        short8 a0 = *(const short8*)(Kb_ + (by0 >> 1));
        short8 a1 = *(const short8*)(Kb_ + (by1 >> 1));
        st[0] = __builtin_amdgcn_mfma_f32_32x32x16_bf16(a0, qf[kc], st[0], 0, 0, 0);
        st[1] = __builtin_amdgcn_mfma_f32_32x32x16_bf16(a1, qf[kc], st[1], 0, 0, 0);
      }
      __builtin_amdgcn_s_setprio(0);

      const float scale2 = 0.08838834764831845f * 1.44269504088896340736f;
      float mx = -1e30f;
#pragma unroll
      for (int kb = 0; kb < 2; ++kb)
#pragma unroll
        for (int r = 0; r < 16; ++r) {
          float s = st[kb][r] * scale2;
          int key = k0 + kb * 32 + (r & 3) + ((r >> 2) << 3) + (hi << 2);
          if (key > q_) s = -1e30f;
          st[kb][r] = s;
          mx = fmaxf(mx, s);
        }
      mx = fmaxf(mx, __shfl_xor(mx, 32, 64));

      if (__any(mx > m_i + 8.f)) {
        float mn  = fmaxf(m_i, mx);
        float esc = exp2f(m_i - mn);
        m_i = mn; l_p *= esc;
#pragma unroll
        for (int db = 0; db < 4; ++db)
#pragma unroll
          for (int r = 0; r < 16; ++r) oacc[db][r] *= esc;
      }
      float sum = 0.f;
#pragma unroll
      for (int kb = 0; kb < 2; ++kb)
#pragma unroll
        for (int r = 0; r < 16; ++r) {
          float e = exp2f(st[kb][r] - m_i);
          st[kb][r] = e;
          sum += e;
        }
      l_p += sum;

      __builtin_amdgcn_s_setprio(1);
#pragma unroll
      for (int kb = 0; kb < 2; ++kb) {
#pragma unroll
        for (int half = 0; half < 2; ++half) {
          const int rb = half * 8;
          u32 w0 = cvtpk(st[kb][rb + 0], st[kb][rb + 1]);
          u32 w1 = cvtpk(st[kb][rb + 2], st[kb][rb + 3]);
          u32 w2 = cvtpk(st[kb][rb + 4], st[kb][rb + 5]);
          u32 w3 = cvtpk(st[kb][rb + 6], st[kb][rb + 7]);
          permswap(w0, w2);
          permswap(w1, w3);
          short8 pf = __builtin_bit_cast(short8, (u32x4){w0, w1, w2, w3});
          const int ktv = kb * 2 + half;
#pragma unroll
          for (int db = 0; db < 4; ++db) {
            int d = db * 32 + l31;
            int by = d * 128 + ((ktv * 32 + hi * 16) ^ swz);
            short8 vf = *(const short8*)(Vb_ + (by >> 1));
            oacc[db] = __builtin_amdgcn_mfma_f32_32x32x16_bf16(vf, pf, oacc[db], 0, 0, 0);
          }
        }
      }
      __builtin_amdgcn_s_setprio(0);
    }
    __syncthreads();
    buf ^= 1;
  }

  float lt  = l_p + __shfl_xor(l_p, 32, 64);
  float inv = 1.f / lt;
#pragma unroll
  for (int db = 0; db < 4; ++db)
#pragma unroll
    for (int g = 0; g < 4; ++g) {
      int d0 = db * 32 + 8 * g + 4 * hi;
      u32x2 pk;
      pk[0] = cvtpk(oacc[db][4 * g + 0] * inv, oacc[db][4 * g + 1] * inv);
      pk[1] = cvtpk(oacc[db][4 * g + 2] * inv, oacc[db][4 * g + 3] * inv);
      *(u32x2*)(O + base + (size_t)q_ * DD + d0) = pk;
    }
#undef STAGE
}

// ---------------- launcher ----------------
extern "C" void kernel_launch(void* const* d_in, const int* in_sizes, int n_in,
                              void* d_out, int out_size, void* d_ws, size_t ws_size,
                              hipStream_t stream) {
  (void)in_sizes; (void)n_in; (void)out_size; (void)ws_size;
  const float* x  = (const float*)d_in[0];
  const float* wq = (const float*)d_in[1];
  const float* wk = (const float*)d_in[2];
  const float* wv = (const float*)d_in[3];
  const float* wo = (const float*)d_in[4];
  const float* fc = (const float*)d_in[5];
  const float* fs = (const float*)d_in[6];
  float* out = (float*)d_out;

  const size_t XBUF = (size_t)MM * DD * 2;     // 16.78 MB
  const size_t WBUF = (size_t)DD * DD * 2;     // 8.39 MB
  char* ws = (char*)d_ws;
  u16* xb   = (u16*)(ws);                      // reused as attn output Ob
  u16* Qb   = (u16*)(ws + XBUF);
  u16* Kb   = (u16*)(ws + 2 * XBUF);
  u16* Vtb  = (u16*)(ws + 3 * XBUF);
  u16* wqkv = (u16*)(ws + 4 * XBUF);           // [6144][2048]
  u16* wob  = (u16*)(ws + 4 * XBUF + 3 * WBUF);
  u16* Ob   = xb;

  const int ncv = (MM * DD) / 4 + 4 * ((DD * DD) / 4);   // 6291456
  cvt_all<<<ncv / 256, 256, 0, stream>>>(x, wq, wk, wv, wo, xb, wqkv, wob);

  // fused QKV projection: C[4096, 6144] with rope/transpose epilogue
  gemm2<4><<<dim3(48, 32), 256, 0, stream>>>(xb, wqkv, Qb, Kb, Vtb, nullptr,
                                             MM, 3 * DD, DD, fc, fs);

  attn_kernel<<<dim3(32, 16), 256, 0, stream>>>(Qb, Kb, Vtb, Ob);

  // O-projection: fp32 out
  gemm2<1><<<dim3(16, 32), 256, 0, stream>>>(Ob, wob, nullptr, nullptr, nullptr, out,
                                             MM, DD, DD, nullptr, nullptr);
}